// Round 6
// baseline (646.493 us; speedup 1.0000x reference)
//
#include <hip/hip_runtime.h>
#include <math.h>
#include <stdint.h>

// N=50000, E=600000, IN_CH=64, HEADS=2, C=64, HC=128, EDGE_DIM=32
// Layouts:
//   q/k/v (bf16 packed uint): [node][c] -> both heads at channel c in one uint
//   wq  (float):  [node][h*32+d]  (wq = We^T q, 64 per node)
//   Wet (float2): [(d*64+c)] -> (We[d][h0*64+c], We[d][h1*64+c])
//   exb (float2): [node][slot] -> (ex_h0, ex_h1) in bucket order (unnormalized)
// All data-derived indices are clamped: no input value can cause OOB.

__device__ __forceinline__ float wave_sum64(float v) {
#pragma unroll
    for (int m = 1; m < 64; m <<= 1) v += __shfl_xor(v, m);
    return v;
}

__device__ __forceinline__ unsigned pack_bf16(float2 v) {
    unsigned a = __builtin_bit_cast(unsigned, v.x);
    unsigned b = __builtin_bit_cast(unsigned, v.y);
    a = (a + 0x7FFFu + ((a >> 16) & 1u)) >> 16;   // RNE
    b = (b + 0x7FFFu + ((b >> 16) & 1u)) >> 16;
    return a | (b << 16);
}
__device__ __forceinline__ float2 unpack_bf16(unsigned p) {
    float x = __builtin_bit_cast(float, p << 16);
    float y = __builtin_bit_cast(float, p & 0xFFFF0000u);
    return make_float2(x, y);
}

// deg zero + weight re-layouts, one launch.
__global__ void k_pre(const float* __restrict__ Wq, const float* __restrict__ Wk,
                      const float* __restrict__ Wv, const float* __restrict__ We,
                      const float* __restrict__ Wp, const float* __restrict__ bq,
                      const float* __restrict__ bk, const float* __restrict__ bv,
                      float* __restrict__ Wqt, float* __restrict__ Wkt,
                      float* __restrict__ Wvt, float* __restrict__ Wet,
                      float* __restrict__ Wpt, float* __restrict__ bqt,
                      float* __restrict__ bkt, float* __restrict__ bvt,
                      int* __restrict__ deg, int n) {
    int idx = blockIdx.x * 256 + threadIdx.x;
    for (int i = idx; i < n; i += gridDim.x * 256) deg[i] = 0;
    if (idx < 8192) {
        // Wq/Wk/Wv: [cin][h*64+c] -> [cin][c*2+h]
        int cin = idx >> 7, j = idx & 127, h = j >> 6, c = j & 63;
        int dst = cin * 128 + c * 2 + h;
        Wqt[dst] = Wq[idx];
        Wkt[dst] = Wk[idx];
        Wvt[dst] = Wv[idx];
        // Wp: [h*64+c][o] -> [(c*2+h)][o]
        int jin = idx >> 6, o = idx & 63, hp = jin >> 6, cp = jin & 63;
        Wpt[(cp * 2 + hp) * 64 + o] = Wp[idx];
    }
    if (idx < 4096) {
        // We: [d][h*64+c] -> [(d*64+c)*2+h]
        int d = idx >> 7, j = idx & 127, h = j >> 6, c = j & 63;
        Wet[(d * 64 + c) * 2 + h] = We[idx];
    }
    if (idx < 128) {
        int h = idx >> 6, c = idx & 63;
        bqt[c * 2 + h] = bq[idx];
        bkt[c * 2 + h] = bk[idx];
        bvt[c * 2 + h] = bv[idx];
    }
}

// Fused LN1 + QKV + wq = We^T q. One wave per EIGHT nodes (weight reuse x8).
__global__ __launch_bounds__(256) void k_qkv(
    const float* __restrict__ x,
    const float* __restrict__ Wqt, const float* __restrict__ Wkt, const float* __restrict__ Wvt,
    const float* __restrict__ bqt, const float* __restrict__ bkt, const float* __restrict__ bvt,
    const float* __restrict__ g1, const float* __restrict__ b1,
    const float* __restrict__ We,   // original [d][h*64+c]
    unsigned* __restrict__ qbf, unsigned* __restrict__ kbf,
    unsigned* __restrict__ vbf, float* __restrict__ wq, int n) {
    __shared__ __align__(16) float hT[4][64][8];     // [wave][cin][node]  8 KB
    __shared__ __align__(16) float qs[4][2][8][64];  // [wave][h][node][c] 16 KB
    int wave = threadIdx.x >> 6, lane = threadIdx.x & 63;
    int node0 = blockIdx.x * 32 + wave * 8;
    if (node0 >= n) return;

    // ---- Phase 1: LayerNorm for 8 nodes (8 lanes per node) ----
    int b = lane >> 3, t = lane & 7;
    int nodeb = node0 + b;
    float4 xa = make_float4(0.f, 0.f, 0.f, 0.f), xb = xa;
    if (nodeb < n) {
        const float4* xp = (const float4*)(x + (size_t)nodeb * 64 + t * 8);
        xa = xp[0]; xb = xp[1];
    }
    float s1 = (xa.x + xa.y) + (xa.z + xa.w) + (xb.x + xb.y) + (xb.z + xb.w);
    float s2 = xa.x*xa.x + xa.y*xa.y + xa.z*xa.z + xa.w*xa.w
             + xb.x*xb.x + xb.y*xb.y + xb.z*xb.z + xb.w*xb.w;
#pragma unroll
    for (int m = 1; m < 8; m <<= 1) {
        s1 += __shfl_xor(s1, m);
        s2 += __shfl_xor(s2, m);
    }
    float mean = s1 * 0.015625f;
    float var  = s2 * 0.015625f - mean * mean;
    float rstd = rsqrtf(var + 1e-5f);
    float4 ga = ((const float4*)(g1 + t * 8))[0];
    float4 gb = ((const float4*)(g1 + t * 8))[1];
    float4 ba = ((const float4*)(b1 + t * 8))[0];
    float4 bb = ((const float4*)(b1 + t * 8))[1];
    float hv[8];
    hv[0] = (xa.x - mean) * rstd * ga.x + ba.x;
    hv[1] = (xa.y - mean) * rstd * ga.y + ba.y;
    hv[2] = (xa.z - mean) * rstd * ga.z + ba.z;
    hv[3] = (xa.w - mean) * rstd * ga.w + ba.w;
    hv[4] = (xb.x - mean) * rstd * gb.x + bb.x;
    hv[5] = (xb.y - mean) * rstd * gb.y + bb.y;
    hv[6] = (xb.z - mean) * rstd * gb.z + bb.z;
    hv[7] = (xb.w - mean) * rstd * gb.w + bb.w;
#pragma unroll
    for (int j = 0; j < 8; ++j) hT[wave][t * 8 + j][b] = hv[j];
    // per-wave LDS, wave-lockstep: no barrier needed

    // ---- Phase 2: QKV projection, 8 nodes per weight load ----
    const float2* Wq2 = (const float2*)Wqt;
    const float2* Wk2 = (const float2*)Wkt;
    const float2* Wv2 = (const float2*)Wvt;
    float2 bqv = ((const float2*)bqt)[lane];
    float2 bkv = ((const float2*)bkt)[lane];
    float2 bvv = ((const float2*)bvt)[lane];
    float2 qa[8], ka[8], va[8];
#pragma unroll
    for (int nb = 0; nb < 8; ++nb) { qa[nb] = bqv; ka[nb] = bkv; va[nb] = bvv; }

#pragma unroll 4
    for (int cin = 0; cin < 64; ++cin) {
        float2 w_q = Wq2[cin * 64 + lane];
        float2 w_k = Wk2[cin * 64 + lane];
        float2 w_v = Wv2[cin * 64 + lane];
        const float4* hp = (const float4*)&hT[wave][cin][0];
        float4 h0 = hp[0], h1 = hp[1];   // b128 broadcast
        float hs[8] = {h0.x, h0.y, h0.z, h0.w, h1.x, h1.y, h1.z, h1.w};
#pragma unroll
        for (int nb = 0; nb < 8; ++nb) {
            qa[nb].x += hs[nb] * w_q.x; qa[nb].y += hs[nb] * w_q.y;
            ka[nb].x += hs[nb] * w_k.x; ka[nb].y += hs[nb] * w_k.y;
            va[nb].x += hs[nb] * w_v.x; va[nb].y += hs[nb] * w_v.y;
        }
    }

    // ---- Phase 3: stores + stage q in LDS for phase 4 ----
#pragma unroll
    for (int nb = 0; nb < 8; ++nb) {
        int nd = node0 + nb;
        if (nd < n) {
            qbf[(size_t)nd * 64 + lane] = pack_bf16(qa[nb]);
            kbf[(size_t)nd * 64 + lane] = pack_bf16(ka[nb]);
            vbf[(size_t)nd * 64 + lane] = pack_bf16(va[nb]);
        }
        qs[wave][0][nb][lane] = qa[nb].x;
        qs[wave][1][nb][lane] = qa[nb].y;
    }

    // ---- Phase 4: wq = We^T q, 8 nodes per We load ----
    int hh = lane >> 5, d = lane & 31;
    const float4* Wr = (const float4*)(We + d * 128 + hh * 64);
    float wqa[8] = {0.f, 0.f, 0.f, 0.f, 0.f, 0.f, 0.f, 0.f};
#pragma unroll 4
    for (int c4 = 0; c4 < 16; ++c4) {
        float4 w = Wr[c4];
#pragma unroll
        for (int nb = 0; nb < 8; ++nb) {
            float4 qv = *(const float4*)&qs[wave][hh][nb][c4 * 4];  // broadcast
            wqa[nb] += w.x * qv.x + w.y * qv.y + w.z * qv.z + w.w * qv.w;
        }
    }
#pragma unroll
    for (int nb = 0; nb < 8; ++nb)
        if (node0 + nb < n) wq[(size_t)(node0 + nb) * 64 + lane] = wqa[nb];
}

// Edge-parallel alpha + bucket build (fused). One wave per edge.
// ex = exp((q.k + wq.ea)/8); lane 0 claims slot, writes bucket + exb in slot order.
__global__ __launch_bounds__(256) void k_alpha(
    const unsigned* __restrict__ qbf, const unsigned* __restrict__ kbf,
    const float* __restrict__ wq, const float* __restrict__ edge_attr,
    const int* __restrict__ ei, int* __restrict__ deg,
    int* __restrict__ bucket, float2* __restrict__ exb, int E, int n) {
    int wave = threadIdx.x >> 6, lane = threadIdx.x & 63;
    int e = blockIdx.x * 4 + wave;
    if (e >= E) return;

    int src = ei[e];
    int tgt = ei[E + e];
    src = min(max(src, 0), n - 1);
    tgt = min(max(tgt, 0), n - 1);

    int slot = 0;
    if (lane == 0) slot = atomicAdd(&deg[tgt], 1);

    float2 q2 = unpack_bf16(qbf[(size_t)tgt * 64 + lane]);
    float2 k2 = unpack_bf16(kbf[(size_t)src * 64 + lane]);
    float wqv = wq[(size_t)tgt * 64 + lane];
    float ead = edge_attr[(size_t)e * 32 + (lane & 31)];
    float t = wqv * ead;

    float r0 = q2.x * k2.x + ((lane < 32) ? t : 0.f);
    float r1 = q2.y * k2.y + ((lane < 32) ? 0.f : t);
#pragma unroll
    for (int m = 1; m < 64; m <<= 1) {
        r0 += __shfl_xor(r0, m);
        r1 += __shfl_xor(r1, m);
    }
    if (lane == 0 && slot < 64) {
        bucket[(size_t)tgt * 64 + slot] = e;
        exb[(size_t)tgt * 64 + slot] =
            make_float2(__expf(r0 * 0.125f), __expf(r1 * 0.125f));
    }
}

// Aggregation + out-proj + residual + LN2 + GELU FFN + residual. One wave/node.
// Per edge: acc += ex*v (bf16 gather), S += ex*ea. Edge-proj recovered as We^T S.
__global__ __launch_bounds__(256) void k_agg(
    const unsigned* __restrict__ vbf, const float2* __restrict__ exb,
    const int* __restrict__ deg, const int* __restrict__ bucket,
    const int* __restrict__ ei, const float* __restrict__ edge_attr,
    const float* __restrict__ Wet,   // float2 per (d*64+c)
    const float* __restrict__ Wpt,
    const float* __restrict__ bp, const float* __restrict__ x,
    const float* __restrict__ g2, const float* __restrict__ b2,
    const float* __restrict__ W1, const float* __restrict__ b1f,
    const float* __restrict__ W2, const float* __restrict__ b2f,
    float* __restrict__ out, int n, int E) {
    __shared__ __align__(16) float sbuf[4][128];
    int wave = threadIdx.x >> 6, lane = threadIdx.x & 63;
    int node = blockIdx.x * 4 + wave;
    if (node >= n) return;

    int dl = lane & 31, hh = lane >> 5;

    // Coalesced preamble: lane i holds edge i's id, src, and ex pair.
    int dcount = min(deg[node], 64);
    int eid_l = 0, src_l = 0;
    float2 exl = make_float2(0.f, 0.f);
    if (lane < dcount) {
        eid_l = bucket[(size_t)node * 64 + lane];
        eid_l = min(max(eid_l, 0), E - 1);
        src_l = ei[eid_l];
        src_l = min(max(src_l, 0), n - 1);
        exl = exb[(size_t)node * 64 + lane];
    }
    float den0 = wave_sum64(exl.x);
    float den1 = wave_sum64(exl.y);

    // Padded 4-wide loop: lanes >= dcount contribute ex=0 -> zero contribution.
    float acc0 = 0.f, acc1 = 0.f, S = 0.f;
    int rounds = (dcount + 3) >> 2;
    for (int r = 0; r < rounds; ++r) {
        int i = r * 4;
        int e0 = __shfl(eid_l, i),     e1 = __shfl(eid_l, i + 1),
            e2 = __shfl(eid_l, i + 2), e3 = __shfl(eid_l, i + 3);
        int s0 = __shfl(src_l, i),     s1 = __shfl(src_l, i + 1),
            s2 = __shfl(src_l, i + 2), s3 = __shfl(src_l, i + 3);
        float x0 = __shfl(exl.x, i),     y0 = __shfl(exl.y, i);
        float x1 = __shfl(exl.x, i + 1), y1 = __shfl(exl.y, i + 1);
        float x2 = __shfl(exl.x, i + 2), y2 = __shfl(exl.y, i + 2);
        float x3 = __shfl(exl.x, i + 3), y3 = __shfl(exl.y, i + 3);
        float2 u0 = unpack_bf16(vbf[(size_t)s0 * 64 + lane]);
        float2 u1 = unpack_bf16(vbf[(size_t)s1 * 64 + lane]);
        float2 u2 = unpack_bf16(vbf[(size_t)s2 * 64 + lane]);
        float2 u3 = unpack_bf16(vbf[(size_t)s3 * 64 + lane]);
        float a0 = edge_attr[(size_t)e0 * 32 + dl];
        float a1 = edge_attr[(size_t)e1 * 32 + dl];
        float a2 = edge_attr[(size_t)e2 * 32 + dl];
        float a3 = edge_attr[(size_t)e3 * 32 + dl];
        acc0 += x0 * u0.x; acc1 += y0 * u0.y;
        acc0 += x1 * u1.x; acc1 += y1 * u1.y;
        acc0 += x2 * u2.x; acc1 += y2 * u2.y;
        acc0 += x3 * u3.x; acc1 += y3 * u3.y;
        S += (hh ? y0 : x0) * a0;
        S += (hh ? y1 : x1) * a1;
        S += (hh ? y2 : x2) * a2;
        S += (hh ? y3 : x3) * a3;
    }

    // B = We^T S : S to LDS interleaved [d*2+h], then per-lane 64 FMA.
    float* row = sbuf[wave];
    row[dl * 2 + hh] = S;
    float B0 = 0.f, B1 = 0.f;
    const float2* We2 = (const float2*)Wet;
    const float2* S2 = (const float2*)row;
#pragma unroll
    for (int d = 0; d < 32; ++d) {
        float2 w = We2[d * 64 + lane];
        float2 s = S2[d];   // LDS b64 broadcast
        B0 += w.x * s.x;
        B1 += w.y * s.y;
    }
    float agg0 = (acc0 + B0) / (den0 + 1e-8f);
    float agg1 = (acc1 + B1) / (den1 + 1e-8f);

    // ---- epilogue ----
    ((float2*)row)[lane] = make_float2(agg0, agg1);  // row[c*2+h]
    float outv = bp[lane] + x[(size_t)node * 64 + lane];
    const float4* row4 = (const float4*)row;
#pragma unroll
    for (int j4 = 0; j4 < 32; ++j4) {
        float4 a = row4[j4];
        outv += a.x * Wpt[(4*j4+0)*64 + lane] + a.y * Wpt[(4*j4+1)*64 + lane]
              + a.z * Wpt[(4*j4+2)*64 + lane] + a.w * Wpt[(4*j4+3)*64 + lane];
    }

    float s1 = wave_sum64(outv);
    float s2v = wave_sum64(outv * outv);
    float mean = s1 * (1.0f / 64.0f);
    float var  = s2v * (1.0f / 64.0f) - mean * mean;
    float rstd = rsqrtf(var + 1e-5f);
    float h2 = (outv - mean) * rstd * g2[lane] + b2[lane];

    row[lane] = h2;
    float f = b1f[lane];
#pragma unroll
    for (int j4 = 0; j4 < 16; ++j4) {
        float4 a = row4[j4];
        f += a.x * W1[(4*j4+0)*64 + lane] + a.y * W1[(4*j4+1)*64 + lane]
           + a.z * W1[(4*j4+2)*64 + lane] + a.w * W1[(4*j4+3)*64 + lane];
    }
    float g = 0.5f * f * (1.0f + erff(f * 0.70710678118654752f));

    row[lane] = g;
    float y = b2f[lane] + outv;
#pragma unroll
    for (int j4 = 0; j4 < 16; ++j4) {
        float4 a = row4[j4];
        y += a.x * W2[(4*j4+0)*64 + lane] + a.y * W2[(4*j4+1)*64 + lane]
           + a.z * W2[(4*j4+2)*64 + lane] + a.w * W2[(4*j4+3)*64 + lane];
    }
    out[(size_t)node * 64 + lane] = y;
}

extern "C" void kernel_launch(void* const* d_in, const int* in_sizes, int n_in,
                              void* d_out, int out_size, void* d_ws, size_t ws_size,
                              hipStream_t stream) {
    const float* x  = (const float*)d_in[0];
    const int*   ei = (const int*)d_in[1];
    const float* ea = (const float*)d_in[2];
    const float* Wq = (const float*)d_in[3];
    const float* bq = (const float*)d_in[4];
    const float* Wk = (const float*)d_in[5];
    const float* bk = (const float*)d_in[6];
    const float* Wv = (const float*)d_in[7];
    const float* bv = (const float*)d_in[8];
    const float* We = (const float*)d_in[9];
    const float* Wp = (const float*)d_in[10];
    const float* bp = (const float*)d_in[11];
    const float* g1 = (const float*)d_in[12];
    const float* b1 = (const float*)d_in[13];
    const float* g2 = (const float*)d_in[14];
    const float* b2 = (const float*)d_in[15];
    const float* W1 = (const float*)d_in[16];
    const float* b1f = (const float*)d_in[17];
    const float* W2 = (const float*)d_in[18];
    const float* b2f = (const float*)d_in[19];

    const int n = in_sizes[0] / 64;   // 50000
    const int E = in_sizes[2] / 32;   // 600000

    // Workspace carve (~90.0 MB; 90.3 MB proven to fit in R3)
    char* p = (char*)d_ws;
    unsigned* qbf = (unsigned*)p; p += (size_t)n * 64 * 4;
    unsigned* kbf = (unsigned*)p; p += (size_t)n * 64 * 4;
    unsigned* vbf = (unsigned*)p; p += (size_t)n * 64 * 4;
    float* wq  = (float*)p; p += (size_t)n * 64 * 4;
    int* deg   = (int*)p;   p += (size_t)n * 4;
    p = (char*)(((uintptr_t)p + 15) & ~(uintptr_t)15);
    int* bucket = (int*)p;  p += (size_t)n * 64 * 4;
    float2* exb = (float2*)p; p += (size_t)n * 64 * 8;
    float* Wqt = (float*)p; p += 8192 * 4;
    float* Wkt = (float*)p; p += 8192 * 4;
    float* Wvt = (float*)p; p += 8192 * 4;
    float* Wet = (float*)p; p += 4096 * 4;
    float* Wpt = (float*)p; p += 8192 * 4;
    float* bqt = (float*)p; p += 128 * 4;
    float* bkt = (float*)p; p += 128 * 4;
    float* bvt = (float*)p; p += 128 * 4;

    k_pre<<<196, 256, 0, stream>>>(Wq, Wk, Wv, We, Wp, bq, bk, bv,
                                   Wqt, Wkt, Wvt, Wet, Wpt, bqt, bkt, bvt, deg, n);
    k_qkv<<<(n + 31) / 32, 256, 0, stream>>>(x, Wqt, Wkt, Wvt, bqt, bkt, bvt,
                                             g1, b1, We, qbf, kbf, vbf, wq, n);
    k_alpha<<<(E + 3) / 4, 256, 0, stream>>>(qbf, kbf, wq, ea, ei,
                                             deg, bucket, exb, E, n);
    k_agg<<<(n + 3) / 4, 256, 0, stream>>>(vbf, exb, deg, bucket, ei, ea,
                                           Wet, Wpt, bp, x, g2, b2,
                                           W1, b1f, W2, b2f, (float*)d_out, n, E);
}

// Round 7
// 595.726 us; speedup vs baseline: 1.0852x; 1.0852x over previous
//
#include <hip/hip_runtime.h>
#include <math.h>
#include <stdint.h>

// N=50000, E=600000, IN_CH=64, HEADS=2, C=64, HC=128, EDGE_DIM=32
// Layouts:
//   q/k/v (bf16 packed uint): [node][c] -> both heads at channel c in one uint
//   wq  (float):  [node][h*32+d]  (wq = We^T q, 64 per node)
//   Wet (float2): [(d*64+c)] -> (We[d][h0*64+c], We[d][h1*64+c])
//   exb (float2): [node][slot] -> (ex_h0, ex_h1) in bucket order (unnormalized)
//   agg (float2): [node][c] -> (h0,h1); flat index cin=c*2+h matches Wpt rows.
//                 ALIASED onto qbf/kbf (dead after k_alpha).
// All data-derived indices are clamped: no input value can cause OOB.

__device__ __forceinline__ float wave_sum64(float v) {
#pragma unroll
    for (int m = 1; m < 64; m <<= 1) v += __shfl_xor(v, m);
    return v;
}

__device__ __forceinline__ unsigned pack_bf16(float2 v) {
    unsigned a = __builtin_bit_cast(unsigned, v.x);
    unsigned b = __builtin_bit_cast(unsigned, v.y);
    a = (a + 0x7FFFu + ((a >> 16) & 1u)) >> 16;   // RNE
    b = (b + 0x7FFFu + ((b >> 16) & 1u)) >> 16;
    return a | (b << 16);
}
__device__ __forceinline__ float2 unpack_bf16(unsigned p) {
    float x = __builtin_bit_cast(float, p << 16);
    float y = __builtin_bit_cast(float, p & 0xFFFF0000u);
    return make_float2(x, y);
}

// deg zero + weight re-layouts, one launch.
__global__ void k_pre(const float* __restrict__ Wq, const float* __restrict__ Wk,
                      const float* __restrict__ Wv, const float* __restrict__ We,
                      const float* __restrict__ Wp, const float* __restrict__ bq,
                      const float* __restrict__ bk, const float* __restrict__ bv,
                      float* __restrict__ Wqt, float* __restrict__ Wkt,
                      float* __restrict__ Wvt, float* __restrict__ Wet,
                      float* __restrict__ Wpt, float* __restrict__ bqt,
                      float* __restrict__ bkt, float* __restrict__ bvt,
                      int* __restrict__ deg, int n) {
    int idx = blockIdx.x * 256 + threadIdx.x;
    for (int i = idx; i < n; i += gridDim.x * 256) deg[i] = 0;
    if (idx < 8192) {
        // Wq/Wk/Wv: [cin][h*64+c] -> [cin][c*2+h]
        int cin = idx >> 7, j = idx & 127, h = j >> 6, c = j & 63;
        int dst = cin * 128 + c * 2 + h;
        Wqt[dst] = Wq[idx];
        Wkt[dst] = Wk[idx];
        Wvt[dst] = Wv[idx];
        // Wp: [h*64+c][o] -> [(c*2+h)][o]
        int jin = idx >> 6, o = idx & 63, hp = jin >> 6, cp = jin & 63;
        Wpt[(cp * 2 + hp) * 64 + o] = Wp[idx];
    }
    if (idx < 4096) {
        // We: [d][h*64+c] -> [(d*64+c)*2+h]
        int d = idx >> 7, j = idx & 127, h = j >> 6, c = j & 63;
        Wet[(d * 64 + c) * 2 + h] = We[idx];
    }
    if (idx < 128) {
        int h = idx >> 6, c = idx & 63;
        bqt[c * 2 + h] = bq[idx];
        bkt[c * 2 + h] = bk[idx];
        bvt[c * 2 + h] = bv[idx];
    }
}

// Fused LN1 + QKV + wq = We^T q. One wave per EIGHT nodes (weight reuse x8).
__global__ __launch_bounds__(256) void k_qkv(
    const float* __restrict__ x,
    const float* __restrict__ Wqt, const float* __restrict__ Wkt, const float* __restrict__ Wvt,
    const float* __restrict__ bqt, const float* __restrict__ bkt, const float* __restrict__ bvt,
    const float* __restrict__ g1, const float* __restrict__ b1,
    const float* __restrict__ We,   // original [d][h*64+c]
    unsigned* __restrict__ qbf, unsigned* __restrict__ kbf,
    unsigned* __restrict__ vbf, float* __restrict__ wq, int n) {
    __shared__ __align__(16) float hT[4][64][8];     // [wave][cin][node]  8 KB
    __shared__ __align__(16) float qs[4][2][8][64];  // [wave][h][node][c] 16 KB
    int wave = threadIdx.x >> 6, lane = threadIdx.x & 63;
    int node0 = blockIdx.x * 32 + wave * 8;
    if (node0 >= n) return;

    // ---- Phase 1: LayerNorm for 8 nodes (8 lanes per node) ----
    int b = lane >> 3, t = lane & 7;
    int nodeb = node0 + b;
    float4 xa = make_float4(0.f, 0.f, 0.f, 0.f), xb = xa;
    if (nodeb < n) {
        const float4* xp = (const float4*)(x + (size_t)nodeb * 64 + t * 8);
        xa = xp[0]; xb = xp[1];
    }
    float s1 = (xa.x + xa.y) + (xa.z + xa.w) + (xb.x + xb.y) + (xb.z + xb.w);
    float s2 = xa.x*xa.x + xa.y*xa.y + xa.z*xa.z + xa.w*xa.w
             + xb.x*xb.x + xb.y*xb.y + xb.z*xb.z + xb.w*xb.w;
#pragma unroll
    for (int m = 1; m < 8; m <<= 1) {
        s1 += __shfl_xor(s1, m);
        s2 += __shfl_xor(s2, m);
    }
    float mean = s1 * 0.015625f;
    float var  = s2 * 0.015625f - mean * mean;
    float rstd = rsqrtf(var + 1e-5f);
    float4 ga = ((const float4*)(g1 + t * 8))[0];
    float4 gb = ((const float4*)(g1 + t * 8))[1];
    float4 ba = ((const float4*)(b1 + t * 8))[0];
    float4 bb = ((const float4*)(b1 + t * 8))[1];
    float hv[8];
    hv[0] = (xa.x - mean) * rstd * ga.x + ba.x;
    hv[1] = (xa.y - mean) * rstd * ga.y + ba.y;
    hv[2] = (xa.z - mean) * rstd * ga.z + ba.z;
    hv[3] = (xa.w - mean) * rstd * ga.w + ba.w;
    hv[4] = (xb.x - mean) * rstd * gb.x + bb.x;
    hv[5] = (xb.y - mean) * rstd * gb.y + bb.y;
    hv[6] = (xb.z - mean) * rstd * gb.z + bb.z;
    hv[7] = (xb.w - mean) * rstd * gb.w + bb.w;
#pragma unroll
    for (int j = 0; j < 8; ++j) hT[wave][t * 8 + j][b] = hv[j];
    // per-wave LDS, wave-lockstep: no barrier needed

    // ---- Phase 2: QKV projection, 8 nodes per weight load ----
    const float2* Wq2 = (const float2*)Wqt;
    const float2* Wk2 = (const float2*)Wkt;
    const float2* Wv2 = (const float2*)Wvt;
    float2 bqv = ((const float2*)bqt)[lane];
    float2 bkv = ((const float2*)bkt)[lane];
    float2 bvv = ((const float2*)bvt)[lane];
    float2 qa[8], ka[8], va[8];
#pragma unroll
    for (int nb = 0; nb < 8; ++nb) { qa[nb] = bqv; ka[nb] = bkv; va[nb] = bvv; }

#pragma unroll 4
    for (int cin = 0; cin < 64; ++cin) {
        float2 w_q = Wq2[cin * 64 + lane];
        float2 w_k = Wk2[cin * 64 + lane];
        float2 w_v = Wv2[cin * 64 + lane];
        const float4* hp = (const float4*)&hT[wave][cin][0];
        float4 h0 = hp[0], h1 = hp[1];   // b128 broadcast
        float hs[8] = {h0.x, h0.y, h0.z, h0.w, h1.x, h1.y, h1.z, h1.w};
#pragma unroll
        for (int nb = 0; nb < 8; ++nb) {
            qa[nb].x += hs[nb] * w_q.x; qa[nb].y += hs[nb] * w_q.y;
            ka[nb].x += hs[nb] * w_k.x; ka[nb].y += hs[nb] * w_k.y;
            va[nb].x += hs[nb] * w_v.x; va[nb].y += hs[nb] * w_v.y;
        }
    }

    // ---- Phase 3: stores + stage q in LDS for phase 4 ----
#pragma unroll
    for (int nb = 0; nb < 8; ++nb) {
        int nd = node0 + nb;
        if (nd < n) {
            qbf[(size_t)nd * 64 + lane] = pack_bf16(qa[nb]);
            kbf[(size_t)nd * 64 + lane] = pack_bf16(ka[nb]);
            vbf[(size_t)nd * 64 + lane] = pack_bf16(va[nb]);
        }
        qs[wave][0][nb][lane] = qa[nb].x;
        qs[wave][1][nb][lane] = qa[nb].y;
    }

    // ---- Phase 4: wq = We^T q, 8 nodes per We load ----
    int hh = lane >> 5, d = lane & 31;
    const float4* Wr = (const float4*)(We + d * 128 + hh * 64);
    float wqa[8] = {0.f, 0.f, 0.f, 0.f, 0.f, 0.f, 0.f, 0.f};
#pragma unroll 4
    for (int c4 = 0; c4 < 16; ++c4) {
        float4 w = Wr[c4];
#pragma unroll
        for (int nb = 0; nb < 8; ++nb) {
            float4 qv = *(const float4*)&qs[wave][hh][nb][c4 * 4];  // broadcast
            wqa[nb] += w.x * qv.x + w.y * qv.y + w.z * qv.z + w.w * qv.w;
        }
    }
#pragma unroll
    for (int nb = 0; nb < 8; ++nb)
        if (node0 + nb < n) wq[(size_t)(node0 + nb) * 64 + lane] = wqa[nb];
}

// Edge-parallel alpha + bucket build (fused). One wave per edge.
// ex = exp((q.k + wq.ea)/8); lane 0 claims slot, writes bucket + exb in slot order.
__global__ __launch_bounds__(256) void k_alpha(
    const unsigned* __restrict__ qbf, const unsigned* __restrict__ kbf,
    const float* __restrict__ wq, const float* __restrict__ edge_attr,
    const int* __restrict__ ei, int* __restrict__ deg,
    int* __restrict__ bucket, float2* __restrict__ exb, int E, int n) {
    int wave = threadIdx.x >> 6, lane = threadIdx.x & 63;
    int e = blockIdx.x * 4 + wave;
    if (e >= E) return;

    int src = ei[e];
    int tgt = ei[E + e];
    src = min(max(src, 0), n - 1);
    tgt = min(max(tgt, 0), n - 1);

    int slot = 0;
    if (lane == 0) slot = atomicAdd(&deg[tgt], 1);

    float2 q2 = unpack_bf16(qbf[(size_t)tgt * 64 + lane]);
    float2 k2 = unpack_bf16(kbf[(size_t)src * 64 + lane]);
    float wqv = wq[(size_t)tgt * 64 + lane];
    float ead = edge_attr[(size_t)e * 32 + (lane & 31)];
    float t = wqv * ead;

    float r0 = q2.x * k2.x + ((lane < 32) ? t : 0.f);
    float r1 = q2.y * k2.y + ((lane < 32) ? 0.f : t);
#pragma unroll
    for (int m = 1; m < 64; m <<= 1) {
        r0 += __shfl_xor(r0, m);
        r1 += __shfl_xor(r1, m);
    }
    if (lane == 0 && slot < 64) {
        bucket[(size_t)tgt * 64 + slot] = e;
        exb[(size_t)tgt * 64 + slot] =
            make_float2(__expf(r0 * 0.125f), __expf(r1 * 0.125f));
    }
}

// Attention aggregation only (epilogue split into k_post). One wave per node.
// Per edge: acc += ex*v (bf16 gather), S += ex*ea. Edge-proj recovered as We^T S.
__global__ __launch_bounds__(256) void k_agg(
    const unsigned* __restrict__ vbf, const float2* __restrict__ exb,
    const int* __restrict__ deg, const int* __restrict__ bucket,
    const int* __restrict__ ei, const float* __restrict__ edge_attr,
    const float* __restrict__ Wet,   // float2 per (d*64+c)
    float2* __restrict__ agg, int n, int E) {
    __shared__ __align__(16) float sbuf[4][64];
    int wave = threadIdx.x >> 6, lane = threadIdx.x & 63;
    int node = blockIdx.x * 4 + wave;
    if (node >= n) return;

    int dl = lane & 31, hh = lane >> 5;

    // Coalesced preamble: lane i holds edge i's id, src, and ex pair.
    int dcount = min(deg[node], 64);
    int eid_l = 0, src_l = 0;
    float2 exl = make_float2(0.f, 0.f);
    if (lane < dcount) {
        eid_l = bucket[(size_t)node * 64 + lane];
        eid_l = min(max(eid_l, 0), E - 1);
        src_l = ei[eid_l];
        src_l = min(max(src_l, 0), n - 1);
        exl = exb[(size_t)node * 64 + lane];
    }
    float den0 = wave_sum64(exl.x);
    float den1 = wave_sum64(exl.y);

    // Padded 4-wide loop: lanes >= dcount contribute ex=0 -> zero contribution.
    float acc0 = 0.f, acc1 = 0.f, S = 0.f;
    int rounds = (dcount + 3) >> 2;
    for (int r = 0; r < rounds; ++r) {
        int i = r * 4;
        int e0 = __shfl(eid_l, i),     e1 = __shfl(eid_l, i + 1),
            e2 = __shfl(eid_l, i + 2), e3 = __shfl(eid_l, i + 3);
        int s0 = __shfl(src_l, i),     s1 = __shfl(src_l, i + 1),
            s2 = __shfl(src_l, i + 2), s3 = __shfl(src_l, i + 3);
        float x0 = __shfl(exl.x, i),     y0 = __shfl(exl.y, i);
        float x1 = __shfl(exl.x, i + 1), y1 = __shfl(exl.y, i + 1);
        float x2 = __shfl(exl.x, i + 2), y2 = __shfl(exl.y, i + 2);
        float x3 = __shfl(exl.x, i + 3), y3 = __shfl(exl.y, i + 3);
        float2 u0 = unpack_bf16(vbf[(size_t)s0 * 64 + lane]);
        float2 u1 = unpack_bf16(vbf[(size_t)s1 * 64 + lane]);
        float2 u2 = unpack_bf16(vbf[(size_t)s2 * 64 + lane]);
        float2 u3 = unpack_bf16(vbf[(size_t)s3 * 64 + lane]);
        float a0 = edge_attr[(size_t)e0 * 32 + dl];
        float a1 = edge_attr[(size_t)e1 * 32 + dl];
        float a2 = edge_attr[(size_t)e2 * 32 + dl];
        float a3 = edge_attr[(size_t)e3 * 32 + dl];
        acc0 += x0 * u0.x; acc1 += y0 * u0.y;
        acc0 += x1 * u1.x; acc1 += y1 * u1.y;
        acc0 += x2 * u2.x; acc1 += y2 * u2.y;
        acc0 += x3 * u3.x; acc1 += y3 * u3.y;
        S += (hh ? y0 : x0) * a0;
        S += (hh ? y1 : x1) * a1;
        S += (hh ? y2 : x2) * a2;
        S += (hh ? y3 : x3) * a3;
    }

    // B = We^T S : S to LDS interleaved [d*2+h], then per-lane 64 FMA.
    float* row = sbuf[wave];
    row[dl * 2 + hh] = S;
    float B0 = 0.f, B1 = 0.f;
    const float2* We2 = (const float2*)Wet;
    const float2* S2 = (const float2*)row;
#pragma unroll
    for (int d = 0; d < 32; ++d) {
        float2 w = We2[d * 64 + lane];
        float2 s = S2[d];   // LDS b64 broadcast
        B0 += w.x * s.x;
        B1 += w.y * s.y;
    }
    float r0 = 1.0f / (den0 + 1e-8f);
    float r1 = 1.0f / (den1 + 1e-8f);
    agg[(size_t)node * 64 + lane] = make_float2((acc0 + B0) * r0, (acc1 + B1) * r1);
}

// Epilogue: out = agg@Wp + bp + x; LN2; GELU-FFN; + residual.  LANE = NODE.
// All weight/bias accesses are wave-uniform -> compiler emits s_load + FMA w/ SGPR:
// weights fetched once per 64 nodes instead of once per node.
__global__ __launch_bounds__(256) void k_post(
    const float* __restrict__ agg,   // [node][128], cin = c*2+h
    const float* __restrict__ Wpt,   // [cin][64]
    const float* __restrict__ bp, const float* __restrict__ x,
    const float* __restrict__ g2, const float* __restrict__ b2,
    const float* __restrict__ W1, const float* __restrict__ b1f,
    const float* __restrict__ W2, const float* __restrict__ b2f,
    float* __restrict__ out, int n) {
    int node = blockIdx.x * 256 + threadIdx.x;
    bool valid = node < n;
    int nd = min(node, n - 1);

    // acc = bp + x (residual 1 folded in)
    float acc[64];
    {
        const float4* xp = (const float4*)(x + (size_t)nd * 64);
#pragma unroll
        for (int c4 = 0; c4 < 16; ++c4) {
            float4 xv = xp[c4];
            acc[4*c4+0] = bp[4*c4+0] + xv.x;
            acc[4*c4+1] = bp[4*c4+1] + xv.y;
            acc[4*c4+2] = bp[4*c4+2] + xv.z;
            acc[4*c4+3] = bp[4*c4+3] + xv.w;
        }
    }

    // acc += agg @ Wp   (128x64; agg per-lane, Wp wave-uniform -> SGPR)
    const float4* ap = (const float4*)(agg + (size_t)nd * 128);
    for (int ch = 0; ch < 8; ++ch) {
        float a[16];
#pragma unroll
        for (int j4 = 0; j4 < 4; ++j4) {
            float4 v = ap[ch * 4 + j4];
            a[4*j4+0] = v.x; a[4*j4+1] = v.y; a[4*j4+2] = v.z; a[4*j4+3] = v.w;
        }
#pragma unroll
        for (int j = 0; j < 16; ++j) {
            const float* wr = Wpt + (ch * 16 + j) * 64;
#pragma unroll
            for (int c = 0; c < 64; ++c) acc[c] += a[j] * wr[c];
        }
    }

    // LN2 (lane-local: all 64 channels live in registers)
    float s1 = 0.f, s2 = 0.f;
#pragma unroll
    for (int c = 0; c < 64; ++c) { s1 += acc[c]; s2 += acc[c] * acc[c]; }
    float mean = s1 * 0.015625f;
    float var  = s2 * 0.015625f - mean * mean;
    float rstd = rsqrtf(var + 1e-5f);
    float h2[64];
#pragma unroll
    for (int c = 0; c < 64; ++c)
        h2[c] = (acc[c] - mean) * rstd * g2[c] + b2[c];

    // f = h2 @ W1 + b1; g = gelu(f)
    float g[64];
#pragma unroll
    for (int c = 0; c < 64; ++c) g[c] = b1f[c];
    for (int ch = 0; ch < 4; ++ch) {
#pragma unroll
        for (int j = 0; j < 16; ++j) {
            int cin = ch * 16 + j;
            const float* wr = W1 + cin * 64;
            float hval = h2[cin];
#pragma unroll
            for (int c = 0; c < 64; ++c) g[c] += hval * wr[c];
        }
    }
#pragma unroll
    for (int c = 0; c < 64; ++c)
        g[c] = 0.5f * g[c] * (1.0f + erff(g[c] * 0.70710678118654752f));

    // y = g @ W2 + b2f + acc (residual 2)
    float y[64];
#pragma unroll
    for (int c = 0; c < 64; ++c) y[c] = b2f[c] + acc[c];
    for (int ch = 0; ch < 4; ++ch) {
#pragma unroll
        for (int j = 0; j < 16; ++j) {
            int cin = ch * 16 + j;
            const float* wr = W2 + cin * 64;
            float gval = g[cin];
#pragma unroll
            for (int c = 0; c < 64; ++c) y[c] += gval * wr[c];
        }
    }

    if (valid) {
        float4* op = (float4*)(out + (size_t)node * 64);
#pragma unroll
        for (int c4 = 0; c4 < 16; ++c4)
            op[c4] = make_float4(y[4*c4+0], y[4*c4+1], y[4*c4+2], y[4*c4+3]);
    }
}

extern "C" void kernel_launch(void* const* d_in, const int* in_sizes, int n_in,
                              void* d_out, int out_size, void* d_ws, size_t ws_size,
                              hipStream_t stream) {
    const float* x  = (const float*)d_in[0];
    const int*   ei = (const int*)d_in[1];
    const float* ea = (const float*)d_in[2];
    const float* Wq = (const float*)d_in[3];
    const float* bq = (const float*)d_in[4];
    const float* Wk = (const float*)d_in[5];
    const float* bk = (const float*)d_in[6];
    const float* Wv = (const float*)d_in[7];
    const float* bv = (const float*)d_in[8];
    const float* We = (const float*)d_in[9];
    const float* Wp = (const float*)d_in[10];
    const float* bp = (const float*)d_in[11];
    const float* g1 = (const float*)d_in[12];
    const float* b1 = (const float*)d_in[13];
    const float* g2 = (const float*)d_in[14];
    const float* b2 = (const float*)d_in[15];
    const float* W1 = (const float*)d_in[16];
    const float* b1f = (const float*)d_in[17];
    const float* W2 = (const float*)d_in[18];
    const float* b2f = (const float*)d_in[19];

    const int n = in_sizes[0] / 64;   // 50000
    const int E = in_sizes[2] / 32;   // 600000

    // Workspace carve (~90.0 MB, same as proven R6 layout).
    // agg (n*128 floats) ALIASES qbf+kbf (dead after k_alpha, reborn in k_agg).
    char* p = (char*)d_ws;
    unsigned* qbf = (unsigned*)p; p += (size_t)n * 64 * 4;
    unsigned* kbf = (unsigned*)p; p += (size_t)n * 64 * 4;
    float* aggb = (float*)qbf;            // alias: n*128 floats == qbf+kbf extent
    unsigned* vbf = (unsigned*)p; p += (size_t)n * 64 * 4;
    float* wq  = (float*)p; p += (size_t)n * 64 * 4;
    int* deg   = (int*)p;   p += (size_t)n * 4;
    p = (char*)(((uintptr_t)p + 15) & ~(uintptr_t)15);
    int* bucket = (int*)p;  p += (size_t)n * 64 * 4;
    float2* exb = (float2*)p; p += (size_t)n * 64 * 8;
    float* Wqt = (float*)p; p += 8192 * 4;
    float* Wkt = (float*)p; p += 8192 * 4;
    float* Wvt = (float*)p; p += 8192 * 4;
    float* Wet = (float*)p; p += 4096 * 4;
    float* Wpt = (float*)p; p += 8192 * 4;
    float* bqt = (float*)p; p += 128 * 4;
    float* bkt = (float*)p; p += 128 * 4;
    float* bvt = (float*)p; p += 128 * 4;

    k_pre<<<196, 256, 0, stream>>>(Wq, Wk, Wv, We, Wp, bq, bk, bv,
                                   Wqt, Wkt, Wvt, Wet, Wpt, bqt, bkt, bvt, deg, n);
    k_qkv<<<(n + 31) / 32, 256, 0, stream>>>(x, Wqt, Wkt, Wvt, bqt, bkt, bvt,
                                             g1, b1, We, qbf, kbf, vbf, wq, n);
    k_alpha<<<(E + 3) / 4, 256, 0, stream>>>(qbf, kbf, wq, ea, ei,
                                             deg, bucket, exb, E, n);
    k_agg<<<(n + 3) / 4, 256, 0, stream>>>(vbf, exb, deg, bucket, ei, ea,
                                           Wet, (float2*)aggb, n, E);
    k_post<<<(n + 255) / 256, 256, 0, stream>>>(aggb, Wpt, bp, x, g2, b2,
                                                W1, b1f, W2, b2f,
                                                (float*)d_out, n);
}

// Round 8
// 522.750 us; speedup vs baseline: 1.2367x; 1.1396x over previous
//
#include <hip/hip_runtime.h>
#include <math.h>
#include <stdint.h>

// N=50000, E=600000, IN_CH=64, HEADS=2, C=64, HC=128, EDGE_DIM=32
// Layouts:
//   q/k/v (bf16 packed uint): [node][c] -> both heads at channel c in one uint
//   wq  (float2): [node*32+d] -> (wq_h0[d], wq_h1[d])   (wq = We^T q)
//   Wet (float2): [(d*64+c)] -> (We[d][h0*64+c], We[d][h1*64+c])
//   exb (float2): [node][slot] -> (ex_h0, ex_h1) in bucket order (unnormalized)
//   agg (float2): [node][c] -> (h0,h1); flat index cin=c*2+h matches Wpt rows.
//                 ALIASED onto qbf/kbf (dead after k_alpha).
// All data-derived indices are clamped: no input value can cause OOB.

__device__ __forceinline__ float wave_sum64(float v) {
#pragma unroll
    for (int m = 1; m < 64; m <<= 1) v += __shfl_xor(v, m);
    return v;
}

__device__ __forceinline__ unsigned pack_bf16(float2 v) {
    unsigned a = __builtin_bit_cast(unsigned, v.x);
    unsigned b = __builtin_bit_cast(unsigned, v.y);
    a = (a + 0x7FFFu + ((a >> 16) & 1u)) >> 16;   // RNE
    b = (b + 0x7FFFu + ((b >> 16) & 1u)) >> 16;
    return a | (b << 16);
}
__device__ __forceinline__ float2 unpack_bf16(unsigned p) {
    float x = __builtin_bit_cast(float, p << 16);
    float y = __builtin_bit_cast(float, p & 0xFFFF0000u);
    return make_float2(x, y);
}

// deg zero + weight re-layouts, one launch.
__global__ void k_pre(const float* __restrict__ Wq, const float* __restrict__ Wk,
                      const float* __restrict__ Wv, const float* __restrict__ We,
                      const float* __restrict__ Wp, const float* __restrict__ bq,
                      const float* __restrict__ bk, const float* __restrict__ bv,
                      float* __restrict__ Wqt, float* __restrict__ Wkt,
                      float* __restrict__ Wvt, float* __restrict__ Wet,
                      float* __restrict__ Wpt, float* __restrict__ bqt,
                      float* __restrict__ bkt, float* __restrict__ bvt,
                      int* __restrict__ deg, int n) {
    int idx = blockIdx.x * 256 + threadIdx.x;
    for (int i = idx; i < n; i += gridDim.x * 256) deg[i] = 0;
    if (idx < 8192) {
        // Wq/Wk/Wv: [cin][h*64+c] -> [cin][c*2+h]
        int cin = idx >> 7, j = idx & 127, h = j >> 6, c = j & 63;
        int dst = cin * 128 + c * 2 + h;
        Wqt[dst] = Wq[idx];
        Wkt[dst] = Wk[idx];
        Wvt[dst] = Wv[idx];
        // Wp: [h*64+c][o] -> [(c*2+h)][o]
        int jin = idx >> 6, o = idx & 63, hp = jin >> 6, cp = jin & 63;
        Wpt[(cp * 2 + hp) * 64 + o] = Wp[idx];
    }
    if (idx < 4096) {
        // We: [d][h*64+c] -> [(d*64+c)*2+h]
        int d = idx >> 7, j = idx & 127, h = j >> 6, c = j & 63;
        Wet[(d * 64 + c) * 2 + h] = We[idx];
    }
    if (idx < 128) {
        int h = idx >> 6, c = idx & 63;
        bqt[c * 2 + h] = bq[idx];
        bkt[c * 2 + h] = bk[idx];
        bvt[c * 2 + h] = bv[idx];
    }
}

// Fused LN1 + QKV + wq = We^T q. One wave per EIGHT nodes (weight reuse x8).
__global__ __launch_bounds__(256) void k_qkv(
    const float* __restrict__ x,
    const float* __restrict__ Wqt, const float* __restrict__ Wkt, const float* __restrict__ Wvt,
    const float* __restrict__ bqt, const float* __restrict__ bkt, const float* __restrict__ bvt,
    const float* __restrict__ g1, const float* __restrict__ b1,
    const float* __restrict__ We,   // original [d][h*64+c]
    unsigned* __restrict__ qbf, unsigned* __restrict__ kbf,
    unsigned* __restrict__ vbf, float* __restrict__ wq, int n) {
    __shared__ __align__(16) float hT[4][64][8];     // [wave][cin][node]  8 KB
    __shared__ __align__(16) float qs[4][2][8][64];  // [wave][h][node][c] 16 KB
    int wave = threadIdx.x >> 6, lane = threadIdx.x & 63;
    int node0 = blockIdx.x * 32 + wave * 8;
    if (node0 >= n) return;

    // ---- Phase 1: LayerNorm for 8 nodes (8 lanes per node) ----
    int b = lane >> 3, t = lane & 7;
    int nodeb = node0 + b;
    float4 xa = make_float4(0.f, 0.f, 0.f, 0.f), xb = xa;
    if (nodeb < n) {
        const float4* xp = (const float4*)(x + (size_t)nodeb * 64 + t * 8);
        xa = xp[0]; xb = xp[1];
    }
    float s1 = (xa.x + xa.y) + (xa.z + xa.w) + (xb.x + xb.y) + (xb.z + xb.w);
    float s2 = xa.x*xa.x + xa.y*xa.y + xa.z*xa.z + xa.w*xa.w
             + xb.x*xb.x + xb.y*xb.y + xb.z*xb.z + xb.w*xb.w;
#pragma unroll
    for (int m = 1; m < 8; m <<= 1) {
        s1 += __shfl_xor(s1, m);
        s2 += __shfl_xor(s2, m);
    }
    float mean = s1 * 0.015625f;
    float var  = s2 * 0.015625f - mean * mean;
    float rstd = rsqrtf(var + 1e-5f);
    float4 ga = ((const float4*)(g1 + t * 8))[0];
    float4 gb = ((const float4*)(g1 + t * 8))[1];
    float4 ba = ((const float4*)(b1 + t * 8))[0];
    float4 bb = ((const float4*)(b1 + t * 8))[1];
    float hv[8];
    hv[0] = (xa.x - mean) * rstd * ga.x + ba.x;
    hv[1] = (xa.y - mean) * rstd * ga.y + ba.y;
    hv[2] = (xa.z - mean) * rstd * ga.z + ba.z;
    hv[3] = (xa.w - mean) * rstd * ga.w + ba.w;
    hv[4] = (xb.x - mean) * rstd * gb.x + bb.x;
    hv[5] = (xb.y - mean) * rstd * gb.y + bb.y;
    hv[6] = (xb.z - mean) * rstd * gb.z + bb.z;
    hv[7] = (xb.w - mean) * rstd * gb.w + bb.w;
#pragma unroll
    for (int j = 0; j < 8; ++j) hT[wave][t * 8 + j][b] = hv[j];
    // per-wave LDS, wave-lockstep: no barrier needed

    // ---- Phase 2: QKV projection, 8 nodes per weight load ----
    const float2* Wq2 = (const float2*)Wqt;
    const float2* Wk2 = (const float2*)Wkt;
    const float2* Wv2 = (const float2*)Wvt;
    float2 bqv = ((const float2*)bqt)[lane];
    float2 bkv = ((const float2*)bkt)[lane];
    float2 bvv = ((const float2*)bvt)[lane];
    float2 qa[8], ka[8], va[8];
#pragma unroll
    for (int nb = 0; nb < 8; ++nb) { qa[nb] = bqv; ka[nb] = bkv; va[nb] = bvv; }

#pragma unroll 4
    for (int cin = 0; cin < 64; ++cin) {
        float2 w_q = Wq2[cin * 64 + lane];
        float2 w_k = Wk2[cin * 64 + lane];
        float2 w_v = Wv2[cin * 64 + lane];
        const float4* hp = (const float4*)&hT[wave][cin][0];
        float4 h0 = hp[0], h1 = hp[1];   // b128 broadcast
        float hs[8] = {h0.x, h0.y, h0.z, h0.w, h1.x, h1.y, h1.z, h1.w};
#pragma unroll
        for (int nb = 0; nb < 8; ++nb) {
            qa[nb].x += hs[nb] * w_q.x; qa[nb].y += hs[nb] * w_q.y;
            ka[nb].x += hs[nb] * w_k.x; ka[nb].y += hs[nb] * w_k.y;
            va[nb].x += hs[nb] * w_v.x; va[nb].y += hs[nb] * w_v.y;
        }
    }

    // ---- Phase 3: stores + stage q in LDS for phase 4 ----
#pragma unroll
    for (int nb = 0; nb < 8; ++nb) {
        int nd = node0 + nb;
        if (nd < n) {
            qbf[(size_t)nd * 64 + lane] = pack_bf16(qa[nb]);
            kbf[(size_t)nd * 64 + lane] = pack_bf16(ka[nb]);
            vbf[(size_t)nd * 64 + lane] = pack_bf16(va[nb]);
        }
        qs[wave][0][nb][lane] = qa[nb].x;
        qs[wave][1][nb][lane] = qa[nb].y;
    }

    // ---- Phase 4: wq = We^T q, 8 nodes per We load; store interleaved [d*2+h] ----
    int hh = lane >> 5, d = lane & 31;
    const float4* Wr = (const float4*)(We + d * 128 + hh * 64);
    float wqa[8] = {0.f, 0.f, 0.f, 0.f, 0.f, 0.f, 0.f, 0.f};
#pragma unroll 4
    for (int c4 = 0; c4 < 16; ++c4) {
        float4 w = Wr[c4];
#pragma unroll
        for (int nb = 0; nb < 8; ++nb) {
            float4 qv = *(const float4*)&qs[wave][hh][nb][c4 * 4];  // broadcast
            wqa[nb] += w.x * qv.x + w.y * qv.y + w.z * qv.z + w.w * qv.w;
        }
    }
#pragma unroll
    for (int nb = 0; nb < 8; ++nb)
        if (node0 + nb < n)
            wq[(size_t)(node0 + nb) * 64 + d * 2 + hh] = wqa[nb];
}

// Edge-parallel alpha + bucket build. TWO edges per wave (32 lanes each).
// Each lane covers channels 2l,2l+1 (both heads); 5-step half-wave butterfly.
// ex = exp((q.k + wq.ea)/8); lane l==0 of each half claims slot, writes records.
__global__ __launch_bounds__(256) void k_alpha(
    const unsigned* __restrict__ qbf, const unsigned* __restrict__ kbf,
    const float* __restrict__ wq,    // float2 [node*32+d]
    const float* __restrict__ edge_attr,
    const int* __restrict__ ei, int* __restrict__ deg,
    int* __restrict__ bucket, float2* __restrict__ exb, int E, int n) {
    int wave = threadIdx.x >> 6, lane = threadIdx.x & 63;
    int sub = lane >> 5, l = lane & 31;
    int e = blockIdx.x * 8 + wave * 2 + sub;
    bool evalid = e < E;
    int ec = min(e, E - 1);

    int src = ei[ec];          // 32 lanes same addr -> broadcast transaction
    int tgt = ei[E + ec];
    src = min(max(src, 0), n - 1);
    tgt = min(max(tgt, 0), n - 1);

    uint2 qq = ((const uint2*)qbf)[(size_t)tgt * 32 + l];
    uint2 kk = ((const uint2*)kbf)[(size_t)src * 32 + l];
    float2 q0 = unpack_bf16(qq.x), q1 = unpack_bf16(qq.y);
    float2 k0 = unpack_bf16(kk.x), k1 = unpack_bf16(kk.y);
    float2 w = ((const float2*)wq)[(size_t)tgt * 32 + l];
    float a = edge_attr[(size_t)ec * 32 + l];

    float r0 = q0.x * k0.x + q1.x * k1.x + w.x * a;
    float r1 = q0.y * k0.y + q1.y * k1.y + w.y * a;
#pragma unroll
    for (int m = 1; m < 32; m <<= 1) {   // masks 1..16 stay within the half-wave
        r0 += __shfl_xor(r0, m);
        r1 += __shfl_xor(r1, m);
    }
    if (l == 0 && evalid) {
        int slot = atomicAdd(&deg[tgt], 1);
        if (slot < 64) {
            bucket[(size_t)tgt * 64 + slot] = ec;
            exb[(size_t)tgt * 64 + slot] =
                make_float2(__expf(r0 * 0.125f), __expf(r1 * 0.125f));
        }
    }
}

// Attention aggregation only (epilogue in k_post). One wave per node.
// Per edge: acc += ex*v (bf16 gather), S += ex*ea. Edge-proj recovered as We^T S.
__global__ __launch_bounds__(256) void k_agg(
    const unsigned* __restrict__ vbf, const float2* __restrict__ exb,
    const int* __restrict__ deg, const int* __restrict__ bucket,
    const int* __restrict__ ei, const float* __restrict__ edge_attr,
    const float* __restrict__ Wet,   // float2 per (d*64+c)
    float2* __restrict__ agg, int n, int E) {
    __shared__ __align__(16) float sbuf[4][64];
    int wave = threadIdx.x >> 6, lane = threadIdx.x & 63;
    int node = blockIdx.x * 4 + wave;
    if (node >= n) return;

    int dl = lane & 31, hh = lane >> 5;

    // Coalesced preamble: lane i holds edge i's id, src, and ex pair.
    int dcount = min(deg[node], 64);
    int eid_l = 0, src_l = 0;
    float2 exl = make_float2(0.f, 0.f);
    if (lane < dcount) {
        eid_l = bucket[(size_t)node * 64 + lane];
        eid_l = min(max(eid_l, 0), E - 1);
        src_l = ei[eid_l];
        src_l = min(max(src_l, 0), n - 1);
        exl = exb[(size_t)node * 64 + lane];
    }
    float den0 = wave_sum64(exl.x);
    float den1 = wave_sum64(exl.y);

    // Padded 4-wide loop: lanes >= dcount contribute ex=0 -> zero contribution.
    float acc0 = 0.f, acc1 = 0.f, S = 0.f;
    int rounds = (dcount + 3) >> 2;
    for (int r = 0; r < rounds; ++r) {
        int i = r * 4;
        int e0 = __shfl(eid_l, i),     e1 = __shfl(eid_l, i + 1),
            e2 = __shfl(eid_l, i + 2), e3 = __shfl(eid_l, i + 3);
        int s0 = __shfl(src_l, i),     s1 = __shfl(src_l, i + 1),
            s2 = __shfl(src_l, i + 2), s3 = __shfl(src_l, i + 3);
        float x0 = __shfl(exl.x, i),     y0 = __shfl(exl.y, i);
        float x1 = __shfl(exl.x, i + 1), y1 = __shfl(exl.y, i + 1);
        float x2 = __shfl(exl.x, i + 2), y2 = __shfl(exl.y, i + 2);
        float x3 = __shfl(exl.x, i + 3), y3 = __shfl(exl.y, i + 3);
        float2 u0 = unpack_bf16(vbf[(size_t)s0 * 64 + lane]);
        float2 u1 = unpack_bf16(vbf[(size_t)s1 * 64 + lane]);
        float2 u2 = unpack_bf16(vbf[(size_t)s2 * 64 + lane]);
        float2 u3 = unpack_bf16(vbf[(size_t)s3 * 64 + lane]);
        float a0 = edge_attr[(size_t)e0 * 32 + dl];
        float a1 = edge_attr[(size_t)e1 * 32 + dl];
        float a2 = edge_attr[(size_t)e2 * 32 + dl];
        float a3 = edge_attr[(size_t)e3 * 32 + dl];
        acc0 += x0 * u0.x; acc1 += y0 * u0.y;
        acc0 += x1 * u1.x; acc1 += y1 * u1.y;
        acc0 += x2 * u2.x; acc1 += y2 * u2.y;
        acc0 += x3 * u3.x; acc1 += y3 * u3.y;
        S += (hh ? y0 : x0) * a0;
        S += (hh ? y1 : x1) * a1;
        S += (hh ? y2 : x2) * a2;
        S += (hh ? y3 : x3) * a3;
    }

    // B = We^T S : S to LDS interleaved [d*2+h], then per-lane 64 FMA.
    float* row = sbuf[wave];
    row[dl * 2 + hh] = S;
    float B0 = 0.f, B1 = 0.f;
    const float2* We2 = (const float2*)Wet;
    const float2* S2 = (const float2*)row;
#pragma unroll
    for (int d = 0; d < 32; ++d) {
        float2 w = We2[d * 64 + lane];
        float2 s = S2[d];   // LDS b64 broadcast
        B0 += w.x * s.x;
        B1 += w.y * s.y;
    }
    float r0 = 1.0f / (den0 + 1e-8f);
    float r1 = 1.0f / (den1 + 1e-8f);
    agg[(size_t)node * 64 + lane] = make_float2((acc0 + B0) * r0, (acc1 + B1) * r1);
}

// Epilogue: out = agg@Wp + bp + x; LN2; GELU-FFN; + residual.  LANE = NODE.
// All weight/bias accesses are wave-uniform -> s_load + FMA with SGPR operands:
// weights fetched once per 64 nodes instead of once per node.
__global__ __launch_bounds__(256) void k_post(
    const float* __restrict__ agg,   // [node][128], cin = c*2+h
    const float* __restrict__ Wpt,   // [cin][64]
    const float* __restrict__ bp, const float* __restrict__ x,
    const float* __restrict__ g2, const float* __restrict__ b2,
    const float* __restrict__ W1, const float* __restrict__ b1f,
    const float* __restrict__ W2, const float* __restrict__ b2f,
    float* __restrict__ out, int n) {
    int node = blockIdx.x * 256 + threadIdx.x;
    bool valid = node < n;
    int nd = min(node, n - 1);

    // acc = bp + x (residual 1 folded in)
    float acc[64];
    {
        const float4* xp = (const float4*)(x + (size_t)nd * 64);
#pragma unroll
        for (int c4 = 0; c4 < 16; ++c4) {
            float4 xv = xp[c4];
            acc[4*c4+0] = bp[4*c4+0] + xv.x;
            acc[4*c4+1] = bp[4*c4+1] + xv.y;
            acc[4*c4+2] = bp[4*c4+2] + xv.z;
            acc[4*c4+3] = bp[4*c4+3] + xv.w;
        }
    }

    // acc += agg @ Wp   (128x64; agg per-lane, Wp wave-uniform -> SGPR)
    const float4* ap = (const float4*)(agg + (size_t)nd * 128);
    for (int ch = 0; ch < 8; ++ch) {
        float a[16];
#pragma unroll
        for (int j4 = 0; j4 < 4; ++j4) {
            float4 v = ap[ch * 4 + j4];
            a[4*j4+0] = v.x; a[4*j4+1] = v.y; a[4*j4+2] = v.z; a[4*j4+3] = v.w;
        }
#pragma unroll
        for (int j = 0; j < 16; ++j) {
            const float* wr = Wpt + (ch * 16 + j) * 64;
#pragma unroll
            for (int c = 0; c < 64; ++c) acc[c] += a[j] * wr[c];
        }
    }

    // LN2 (lane-local: all 64 channels live in registers)
    float s1 = 0.f, s2 = 0.f;
#pragma unroll
    for (int c = 0; c < 64; ++c) { s1 += acc[c]; s2 += acc[c] * acc[c]; }
    float mean = s1 * 0.015625f;
    float var  = s2 * 0.015625f - mean * mean;
    float rstd = rsqrtf(var + 1e-5f);
    float h2[64];
#pragma unroll
    for (int c = 0; c < 64; ++c)
        h2[c] = (acc[c] - mean) * rstd * g2[c] + b2[c];

    // f = h2 @ W1 + b1; g = gelu(f)
    float g[64];
#pragma unroll
    for (int c = 0; c < 64; ++c) g[c] = b1f[c];
    for (int ch = 0; ch < 4; ++ch) {
#pragma unroll
        for (int j = 0; j < 16; ++j) {
            int cin = ch * 16 + j;
            const float* wr = W1 + cin * 64;
            float hval = h2[cin];
#pragma unroll
            for (int c = 0; c < 64; ++c) g[c] += hval * wr[c];
        }
    }
#pragma unroll
    for (int c = 0; c < 64; ++c)
        g[c] = 0.5f * g[c] * (1.0f + erff(g[c] * 0.70710678118654752f));

    // y = g @ W2 + b2f + acc (residual 2)
    float y[64];
#pragma unroll
    for (int c = 0; c < 64; ++c) y[c] = b2f[c] + acc[c];
    for (int ch = 0; ch < 4; ++ch) {
#pragma unroll
        for (int j = 0; j < 16; ++j) {
            int cin = ch * 16 + j;
            const float* wr = W2 + cin * 64;
            float gval = g[cin];
#pragma unroll
            for (int c = 0; c < 64; ++c) y[c] += gval * wr[c];
        }
    }

    if (valid) {
        float4* op = (float4*)(out + (size_t)node * 64);
#pragma unroll
        for (int c4 = 0; c4 < 16; ++c4)
            op[c4] = make_float4(y[4*c4+0], y[4*c4+1], y[4*c4+2], y[4*c4+3]);
    }
}

extern "C" void kernel_launch(void* const* d_in, const int* in_sizes, int n_in,
                              void* d_out, int out_size, void* d_ws, size_t ws_size,
                              hipStream_t stream) {
    const float* x  = (const float*)d_in[0];
    const int*   ei = (const int*)d_in[1];
    const float* ea = (const float*)d_in[2];
    const float* Wq = (const float*)d_in[3];
    const float* bq = (const float*)d_in[4];
    const float* Wk = (const float*)d_in[5];
    const float* bk = (const float*)d_in[6];
    const float* Wv = (const float*)d_in[7];
    const float* bv = (const float*)d_in[8];
    const float* We = (const float*)d_in[9];
    const float* Wp = (const float*)d_in[10];
    const float* bp = (const float*)d_in[11];
    const float* g1 = (const float*)d_in[12];
    const float* b1 = (const float*)d_in[13];
    const float* g2 = (const float*)d_in[14];
    const float* b2 = (const float*)d_in[15];
    const float* W1 = (const float*)d_in[16];
    const float* b1f = (const float*)d_in[17];
    const float* W2 = (const float*)d_in[18];
    const float* b2f = (const float*)d_in[19];

    const int n = in_sizes[0] / 64;   // 50000
    const int E = in_sizes[2] / 32;   // 600000

    // Workspace carve (~90.0 MB, proven layout).
    // agg (n*128 floats) ALIASES qbf+kbf (dead after k_alpha, reborn in k_agg).
    char* p = (char*)d_ws;
    unsigned* qbf = (unsigned*)p; p += (size_t)n * 64 * 4;
    unsigned* kbf = (unsigned*)p; p += (size_t)n * 64 * 4;
    float* aggb = (float*)qbf;            // alias: n*128 floats == qbf+kbf extent
    unsigned* vbf = (unsigned*)p; p += (size_t)n * 64 * 4;
    float* wq  = (float*)p; p += (size_t)n * 64 * 4;
    int* deg   = (int*)p;   p += (size_t)n * 4;
    p = (char*)(((uintptr_t)p + 15) & ~(uintptr_t)15);
    int* bucket = (int*)p;  p += (size_t)n * 64 * 4;
    float2* exb = (float2*)p; p += (size_t)n * 64 * 8;
    float* Wqt = (float*)p; p += 8192 * 4;
    float* Wkt = (float*)p; p += 8192 * 4;
    float* Wvt = (float*)p; p += 8192 * 4;
    float* Wet = (float*)p; p += 4096 * 4;
    float* Wpt = (float*)p; p += 8192 * 4;
    float* bqt = (float*)p; p += 128 * 4;
    float* bkt = (float*)p; p += 128 * 4;
    float* bvt = (float*)p; p += 128 * 4;

    k_pre<<<196, 256, 0, stream>>>(Wq, Wk, Wv, We, Wp, bq, bk, bv,
                                   Wqt, Wkt, Wvt, Wet, Wpt, bqt, bkt, bvt, deg, n);
    k_qkv<<<(n + 31) / 32, 256, 0, stream>>>(x, Wqt, Wkt, Wvt, bqt, bkt, bvt,
                                             g1, b1, We, qbf, kbf, vbf, wq, n);
    k_alpha<<<(E + 7) / 8, 256, 0, stream>>>(qbf, kbf, wq, ea, ei,
                                             deg, bucket, exb, E, n);
    k_agg<<<(n + 3) / 4, 256, 0, stream>>>(vbf, exb, deg, bucket, ei, ea,
                                           Wet, (float2*)aggb, n, E);
    k_post<<<(n + 255) / 256, 256, 0, stream>>>(aggb, Wpt, bp, x, g2, b2,
                                                W1, b1f, W2, b2f,
                                                (float*)d_out, n);
}

// Round 9
// 489.390 us; speedup vs baseline: 1.3210x; 1.0682x over previous
//
#include <hip/hip_runtime.h>
#include <math.h>
#include <stdint.h>

// N=50000, E=600000, IN_CH=64, HEADS=2, C=64, HC=128, EDGE_DIM=32
// Layouts:
//   qx  (uint/float mix): [node][128 dwords] = 64 uints bf16-packed q (both heads
//        per channel) followed by 64 floats wq interleaved [d*2+h]. One 512 B
//        record per node -> single contiguous tgt-side gather in k_alpha.
//   k/v (bf16 packed uint): [node][c] -> both heads at channel c in one uint
//   Wet (float2): [(d*64+c)] -> (We[d][h0*64+c], We[d][h1*64+c])
//   exb (float2): [node][slot] -> (ex_h0, ex_h1) in bucket order (unnormalized)
//   agg (float2): [node][c] -> (h0,h1); ALIASES qx exactly (dead after k_alpha).
// All data-derived indices are clamped: no input value can cause OOB.

__device__ __forceinline__ float wave_sum64(float v) {
#pragma unroll
    for (int m = 1; m < 64; m <<= 1) v += __shfl_xor(v, m);
    return v;
}

__device__ __forceinline__ unsigned pack_bf16(float2 v) {
    unsigned a = __builtin_bit_cast(unsigned, v.x);
    unsigned b = __builtin_bit_cast(unsigned, v.y);
    a = (a + 0x7FFFu + ((a >> 16) & 1u)) >> 16;   // RNE
    b = (b + 0x7FFFu + ((b >> 16) & 1u)) >> 16;
    return a | (b << 16);
}
__device__ __forceinline__ float2 unpack_bf16(unsigned p) {
    float x = __builtin_bit_cast(float, p << 16);
    float y = __builtin_bit_cast(float, p & 0xFFFF0000u);
    return make_float2(x, y);
}

// deg zero + weight re-layouts, one launch.
__global__ void k_pre(const float* __restrict__ Wq, const float* __restrict__ Wk,
                      const float* __restrict__ Wv, const float* __restrict__ We,
                      const float* __restrict__ Wp, const float* __restrict__ bq,
                      const float* __restrict__ bk, const float* __restrict__ bv,
                      float* __restrict__ Wqt, float* __restrict__ Wkt,
                      float* __restrict__ Wvt, float* __restrict__ Wet,
                      float* __restrict__ Wpt, float* __restrict__ bqt,
                      float* __restrict__ bkt, float* __restrict__ bvt,
                      int* __restrict__ deg, int n) {
    int idx = blockIdx.x * 256 + threadIdx.x;
    for (int i = idx; i < n; i += gridDim.x * 256) deg[i] = 0;
    if (idx < 8192) {
        // Wq/Wk/Wv: [cin][h*64+c] -> [cin][c*2+h]
        int cin = idx >> 7, j = idx & 127, h = j >> 6, c = j & 63;
        int dst = cin * 128 + c * 2 + h;
        Wqt[dst] = Wq[idx];
        Wkt[dst] = Wk[idx];
        Wvt[dst] = Wv[idx];
        // Wp: [h*64+c][o] -> [(c*2+h)][o]
        int jin = idx >> 6, o = idx & 63, hp = jin >> 6, cp = jin & 63;
        Wpt[(cp * 2 + hp) * 64 + o] = Wp[idx];
    }
    if (idx < 4096) {
        // We: [d][h*64+c] -> [(d*64+c)*2+h]
        int d = idx >> 7, j = idx & 127, h = j >> 6, c = j & 63;
        Wet[(d * 64 + c) * 2 + h] = We[idx];
    }
    if (idx < 128) {
        int h = idx >> 6, c = idx & 63;
        bqt[c * 2 + h] = bq[idx];
        bkt[c * 2 + h] = bk[idx];
        bvt[c * 2 + h] = bv[idx];
    }
}

// Fused LN1 + QKV + wq = We^T q. One wave per EIGHT nodes (weight reuse x8).
__global__ __launch_bounds__(256) void k_qkv(
    const float* __restrict__ x,
    const float* __restrict__ Wqt, const float* __restrict__ Wkt, const float* __restrict__ Wvt,
    const float* __restrict__ bqt, const float* __restrict__ bkt, const float* __restrict__ bvt,
    const float* __restrict__ g1, const float* __restrict__ b1,
    const float* __restrict__ We,   // original [d][h*64+c]
    unsigned* __restrict__ qx, unsigned* __restrict__ kbf,
    unsigned* __restrict__ vbf, int n) {
    __shared__ __align__(16) float hT[4][64][8];     // [wave][cin][node]  8 KB
    __shared__ __align__(16) float qs[4][2][8][64];  // [wave][h][node][c] 16 KB
    int wave = threadIdx.x >> 6, lane = threadIdx.x & 63;
    int node0 = blockIdx.x * 32 + wave * 8;
    if (node0 >= n) return;

    // ---- Phase 1: LayerNorm for 8 nodes (8 lanes per node) ----
    int b = lane >> 3, t = lane & 7;
    int nodeb = node0 + b;
    float4 xa = make_float4(0.f, 0.f, 0.f, 0.f), xb = xa;
    if (nodeb < n) {
        const float4* xp = (const float4*)(x + (size_t)nodeb * 64 + t * 8);
        xa = xp[0]; xb = xp[1];
    }
    float s1 = (xa.x + xa.y) + (xa.z + xa.w) + (xb.x + xb.y) + (xb.z + xb.w);
    float s2 = xa.x*xa.x + xa.y*xa.y + xa.z*xa.z + xa.w*xa.w
             + xb.x*xb.x + xb.y*xb.y + xb.z*xb.z + xb.w*xb.w;
#pragma unroll
    for (int m = 1; m < 8; m <<= 1) {
        s1 += __shfl_xor(s1, m);
        s2 += __shfl_xor(s2, m);
    }
    float mean = s1 * 0.015625f;
    float var  = s2 * 0.015625f - mean * mean;
    float rstd = rsqrtf(var + 1e-5f);
    float4 ga = ((const float4*)(g1 + t * 8))[0];
    float4 gb = ((const float4*)(g1 + t * 8))[1];
    float4 ba = ((const float4*)(b1 + t * 8))[0];
    float4 bb = ((const float4*)(b1 + t * 8))[1];
    float hv[8];
    hv[0] = (xa.x - mean) * rstd * ga.x + ba.x;
    hv[1] = (xa.y - mean) * rstd * ga.y + ba.y;
    hv[2] = (xa.z - mean) * rstd * ga.z + ba.z;
    hv[3] = (xa.w - mean) * rstd * ga.w + ba.w;
    hv[4] = (xb.x - mean) * rstd * gb.x + bb.x;
    hv[5] = (xb.y - mean) * rstd * gb.y + bb.y;
    hv[6] = (xb.z - mean) * rstd * gb.z + bb.z;
    hv[7] = (xb.w - mean) * rstd * gb.w + bb.w;
#pragma unroll
    for (int j = 0; j < 8; ++j) hT[wave][t * 8 + j][b] = hv[j];
    // per-wave LDS, wave-lockstep: no barrier needed

    // ---- Phase 2: QKV projection, 8 nodes per weight load ----
    const float2* Wq2 = (const float2*)Wqt;
    const float2* Wk2 = (const float2*)Wkt;
    const float2* Wv2 = (const float2*)Wvt;
    float2 bqv = ((const float2*)bqt)[lane];
    float2 bkv = ((const float2*)bkt)[lane];
    float2 bvv = ((const float2*)bvt)[lane];
    float2 qa[8], ka[8], va[8];
#pragma unroll
    for (int nb = 0; nb < 8; ++nb) { qa[nb] = bqv; ka[nb] = bkv; va[nb] = bvv; }

#pragma unroll 4
    for (int cin = 0; cin < 64; ++cin) {
        float2 w_q = Wq2[cin * 64 + lane];
        float2 w_k = Wk2[cin * 64 + lane];
        float2 w_v = Wv2[cin * 64 + lane];
        const float4* hp = (const float4*)&hT[wave][cin][0];
        float4 h0 = hp[0], h1 = hp[1];   // b128 broadcast
        float hs[8] = {h0.x, h0.y, h0.z, h0.w, h1.x, h1.y, h1.z, h1.w};
#pragma unroll
        for (int nb = 0; nb < 8; ++nb) {
            qa[nb].x += hs[nb] * w_q.x; qa[nb].y += hs[nb] * w_q.y;
            ka[nb].x += hs[nb] * w_k.x; ka[nb].y += hs[nb] * w_k.y;
            va[nb].x += hs[nb] * w_v.x; va[nb].y += hs[nb] * w_v.y;
        }
    }

    // ---- Phase 3: stores + stage q in LDS for phase 4 ----
#pragma unroll
    for (int nb = 0; nb < 8; ++nb) {
        int nd = node0 + nb;
        if (nd < n) {
            qx[(size_t)nd * 128 + lane] = pack_bf16(qa[nb]);
            kbf[(size_t)nd * 64 + lane] = pack_bf16(ka[nb]);
            vbf[(size_t)nd * 64 + lane] = pack_bf16(va[nb]);
        }
        qs[wave][0][nb][lane] = qa[nb].x;
        qs[wave][1][nb][lane] = qa[nb].y;
    }

    // ---- Phase 4: wq = We^T q -> qx[node][64 + d*2 + h], 8 nodes per We load ----
    int hh = lane >> 5, d = lane & 31;
    const float4* Wr = (const float4*)(We + d * 128 + hh * 64);
    float wqa[8] = {0.f, 0.f, 0.f, 0.f, 0.f, 0.f, 0.f, 0.f};
#pragma unroll 4
    for (int c4 = 0; c4 < 16; ++c4) {
        float4 w = Wr[c4];
#pragma unroll
        for (int nb = 0; nb < 8; ++nb) {
            float4 qv = *(const float4*)&qs[wave][hh][nb][c4 * 4];  // broadcast
            wqa[nb] += w.x * qv.x + w.y * qv.y + w.z * qv.z + w.w * qv.w;
        }
    }
#pragma unroll
    for (int nb = 0; nb < 8; ++nb)
        if (node0 + nb < n)
            ((float*)qx)[(size_t)(node0 + nb) * 128 + 64 + d * 2 + hh] = wqa[nb];
}

// Edge-parallel alpha + bucket build. FOUR edges per wave (16 lanes each).
// Lane l in [0,16): q/k channels 4l..4l+3 (uint4), wq dims 2l,2l+1 (float4),
// ea dims 2l,2l+1 (float2). 4-step butterfly within the 16-lane group.
// ex = exp((q.k + wq.ea)/8); lane l==0 claims slot, writes bucket + exb.
__global__ __launch_bounds__(256) void k_alpha(
    const unsigned* __restrict__ qx, const unsigned* __restrict__ kbf,
    const float* __restrict__ edge_attr,
    const int* __restrict__ ei, int* __restrict__ deg,
    int* __restrict__ bucket, float2* __restrict__ exb, int E, int n) {
    int wave = threadIdx.x >> 6, lane = threadIdx.x & 63;
    int sub = lane >> 4, l = lane & 15;
    int e = blockIdx.x * 16 + wave * 4 + sub;
    bool evalid = e < E;
    int ec = min(e, E - 1);

    int src = ei[ec];          // 16 lanes same addr -> broadcast transaction
    int tgt = ei[E + ec];
    src = min(max(src, 0), n - 1);
    tgt = min(max(tgt, 0), n - 1);

    const uint4* qx4 = (const uint4*)qx;
    uint4 qq = qx4[(size_t)tgt * 32 + l];              // q channels 4l..4l+3
    float4 w = ((const float4*)qx)[(size_t)tgt * 32 + 16 + l];  // wq dims 2l,2l+1
    uint4 kk = ((const uint4*)kbf)[(size_t)src * 16 + l];
    float2 a = ((const float2*)edge_attr)[(size_t)ec * 16 + l];

    float2 q0 = unpack_bf16(qq.x), q1 = unpack_bf16(qq.y),
           q2 = unpack_bf16(qq.z), q3 = unpack_bf16(qq.w);
    float2 k0 = unpack_bf16(kk.x), k1 = unpack_bf16(kk.y),
           k2 = unpack_bf16(kk.z), k3 = unpack_bf16(kk.w);

    float r0 = q0.x * k0.x + q1.x * k1.x + q2.x * k2.x + q3.x * k3.x
             + w.x * a.x + w.z * a.y;
    float r1 = q0.y * k0.y + q1.y * k1.y + q2.y * k2.y + q3.y * k3.y
             + w.y * a.x + w.w * a.y;
#pragma unroll
    for (int m = 1; m < 16; m <<= 1) {   // masks 1..8 stay within the 16-lane group
        r0 += __shfl_xor(r0, m);
        r1 += __shfl_xor(r1, m);
    }
    if (l == 0 && evalid) {
        int slot = atomicAdd(&deg[tgt], 1);
        if (slot < 64) {
            bucket[(size_t)tgt * 64 + slot] = ec;
            exb[(size_t)tgt * 64 + slot] =
                make_float2(__expf(r0 * 0.125f), __expf(r1 * 0.125f));
        }
    }
}

// Attention aggregation only (epilogue in k_post). One wave per node.
// Per edge: acc += ex*v (bf16 gather), S += ex*ea. Edge-proj recovered as We^T S.
__global__ __launch_bounds__(256) void k_agg(
    const unsigned* __restrict__ vbf, const float2* __restrict__ exb,
    const int* __restrict__ deg, const int* __restrict__ bucket,
    const int* __restrict__ ei, const float* __restrict__ edge_attr,
    const float* __restrict__ Wet,   // float2 per (d*64+c)
    float2* __restrict__ agg, int n, int E) {
    __shared__ __align__(16) float sbuf[4][64];
    int wave = threadIdx.x >> 6, lane = threadIdx.x & 63;
    int node = blockIdx.x * 4 + wave;
    if (node >= n) return;

    int dl = lane & 31, hh = lane >> 5;

    // Coalesced preamble: lane i holds edge i's id, src, and ex pair.
    int dcount = min(deg[node], 64);
    int eid_l = 0, src_l = 0;
    float2 exl = make_float2(0.f, 0.f);
    if (lane < dcount) {
        eid_l = bucket[(size_t)node * 64 + lane];
        eid_l = min(max(eid_l, 0), E - 1);
        src_l = ei[eid_l];
        src_l = min(max(src_l, 0), n - 1);
        exl = exb[(size_t)node * 64 + lane];
    }
    float den0 = wave_sum64(exl.x);
    float den1 = wave_sum64(exl.y);

    // Padded 4-wide loop: lanes >= dcount contribute ex=0 -> zero contribution.
    float acc0 = 0.f, acc1 = 0.f, S = 0.f;
    int rounds = (dcount + 3) >> 2;
    for (int r = 0; r < rounds; ++r) {
        int i = r * 4;
        int e0 = __shfl(eid_l, i),     e1 = __shfl(eid_l, i + 1),
            e2 = __shfl(eid_l, i + 2), e3 = __shfl(eid_l, i + 3);
        int s0 = __shfl(src_l, i),     s1 = __shfl(src_l, i + 1),
            s2 = __shfl(src_l, i + 2), s3 = __shfl(src_l, i + 3);
        float x0 = __shfl(exl.x, i),     y0 = __shfl(exl.y, i);
        float x1 = __shfl(exl.x, i + 1), y1 = __shfl(exl.y, i + 1);
        float x2 = __shfl(exl.x, i + 2), y2 = __shfl(exl.y, i + 2);
        float x3 = __shfl(exl.x, i + 3), y3 = __shfl(exl.y, i + 3);
        float2 u0 = unpack_bf16(vbf[(size_t)s0 * 64 + lane]);
        float2 u1 = unpack_bf16(vbf[(size_t)s1 * 64 + lane]);
        float2 u2 = unpack_bf16(vbf[(size_t)s2 * 64 + lane]);
        float2 u3 = unpack_bf16(vbf[(size_t)s3 * 64 + lane]);
        float a0 = edge_attr[(size_t)e0 * 32 + dl];
        float a1 = edge_attr[(size_t)e1 * 32 + dl];
        float a2 = edge_attr[(size_t)e2 * 32 + dl];
        float a3 = edge_attr[(size_t)e3 * 32 + dl];
        acc0 += x0 * u0.x; acc1 += y0 * u0.y;
        acc0 += x1 * u1.x; acc1 += y1 * u1.y;
        acc0 += x2 * u2.x; acc1 += y2 * u2.y;
        acc0 += x3 * u3.x; acc1 += y3 * u3.y;
        S += (hh ? y0 : x0) * a0;
        S += (hh ? y1 : x1) * a1;
        S += (hh ? y2 : x2) * a2;
        S += (hh ? y3 : x3) * a3;
    }

    // B = We^T S : S to LDS interleaved [d*2+h], then per-lane 64 FMA.
    float* row = sbuf[wave];
    row[dl * 2 + hh] = S;
    float B0 = 0.f, B1 = 0.f;
    const float2* We2 = (const float2*)Wet;
    const float2* S2 = (const float2*)row;
#pragma unroll
    for (int d = 0; d < 32; ++d) {
        float2 w = We2[d * 64 + lane];
        float2 s = S2[d];   // LDS b64 broadcast
        B0 += w.x * s.x;
        B1 += w.y * s.y;
    }
    float r0 = 1.0f / (den0 + 1e-8f);
    float r1 = 1.0f / (den1 + 1e-8f);
    agg[(size_t)node * 64 + lane] = make_float2((acc0 + B0) * r0, (acc1 + B1) * r1);
}

// Epilogue: out = agg@Wp + bp + x; LN2; GELU-FFN; + residual.  LANE = NODE.
// All weight/bias accesses are wave-uniform -> s_load + FMA with SGPR operands:
// weights fetched once per 64 nodes instead of once per node.
__global__ __launch_bounds__(256) void k_post(
    const float* __restrict__ agg,   // [node][128], cin = c*2+h
    const float* __restrict__ Wpt,   // [cin][64]
    const float* __restrict__ bp, const float* __restrict__ x,
    const float* __restrict__ g2, const float* __restrict__ b2,
    const float* __restrict__ W1, const float* __restrict__ b1f,
    const float* __restrict__ W2, const float* __restrict__ b2f,
    float* __restrict__ out, int n) {
    int node = blockIdx.x * 256 + threadIdx.x;
    bool valid = node < n;
    int nd = min(node, n - 1);

    // acc = bp + x (residual 1 folded in)
    float acc[64];
    {
        const float4* xp = (const float4*)(x + (size_t)nd * 64);
#pragma unroll
        for (int c4 = 0; c4 < 16; ++c4) {
            float4 xv = xp[c4];
            acc[4*c4+0] = bp[4*c4+0] + xv.x;
            acc[4*c4+1] = bp[4*c4+1] + xv.y;
            acc[4*c4+2] = bp[4*c4+2] + xv.z;
            acc[4*c4+3] = bp[4*c4+3] + xv.w;
        }
    }

    // acc += agg @ Wp   (128x64; agg per-lane, Wp wave-uniform -> SGPR)
    const float4* ap = (const float4*)(agg + (size_t)nd * 128);
    for (int ch = 0; ch < 8; ++ch) {
        float a[16];
#pragma unroll
        for (int j4 = 0; j4 < 4; ++j4) {
            float4 v = ap[ch * 4 + j4];
            a[4*j4+0] = v.x; a[4*j4+1] = v.y; a[4*j4+2] = v.z; a[4*j4+3] = v.w;
        }
#pragma unroll
        for (int j = 0; j < 16; ++j) {
            const float* wr = Wpt + (ch * 16 + j) * 64;
#pragma unroll
            for (int c = 0; c < 64; ++c) acc[c] += a[j] * wr[c];
        }
    }

    // LN2 (lane-local: all 64 channels live in registers)
    float s1 = 0.f, s2 = 0.f;
#pragma unroll
    for (int c = 0; c < 64; ++c) { s1 += acc[c]; s2 += acc[c] * acc[c]; }
    float mean = s1 * 0.015625f;
    float var  = s2 * 0.015625f - mean * mean;
    float rstd = rsqrtf(var + 1e-5f);
    float h2[64];
#pragma unroll
    for (int c = 0; c < 64; ++c)
        h2[c] = (acc[c] - mean) * rstd * g2[c] + b2[c];

    // f = h2 @ W1 + b1; g = gelu(f)
    float g[64];
#pragma unroll
    for (int c = 0; c < 64; ++c) g[c] = b1f[c];
    for (int ch = 0; ch < 4; ++ch) {
#pragma unroll
        for (int j = 0; j < 16; ++j) {
            int cin = ch * 16 + j;
            const float* wr = W1 + cin * 64;
            float hval = h2[cin];
#pragma unroll
            for (int c = 0; c < 64; ++c) g[c] += hval * wr[c];
        }
    }
#pragma unroll
    for (int c = 0; c < 64; ++c)
        g[c] = 0.5f * g[c] * (1.0f + erff(g[c] * 0.70710678118654752f));

    // y = g @ W2 + b2f + acc (residual 2)
    float y[64];
#pragma unroll
    for (int c = 0; c < 64; ++c) y[c] = b2f[c] + acc[c];
    for (int ch = 0; ch < 4; ++ch) {
#pragma unroll
        for (int j = 0; j < 16; ++j) {
            int cin = ch * 16 + j;
            const float* wr = W2 + cin * 64;
            float gval = g[cin];
#pragma unroll
            for (int c = 0; c < 64; ++c) y[c] += gval * wr[c];
        }
    }

    if (valid) {
        float4* op = (float4*)(out + (size_t)node * 64);
#pragma unroll
        for (int c4 = 0; c4 < 16; ++c4)
            op[c4] = make_float4(y[4*c4+0], y[4*c4+1], y[4*c4+2], y[4*c4+3]);
    }
}

extern "C" void kernel_launch(void* const* d_in, const int* in_sizes, int n_in,
                              void* d_out, int out_size, void* d_ws, size_t ws_size,
                              hipStream_t stream) {
    const float* x  = (const float*)d_in[0];
    const int*   ei = (const int*)d_in[1];
    const float* ea = (const float*)d_in[2];
    const float* Wq = (const float*)d_in[3];
    const float* bq = (const float*)d_in[4];
    const float* Wk = (const float*)d_in[5];
    const float* bk = (const float*)d_in[6];
    const float* Wv = (const float*)d_in[7];
    const float* bv = (const float*)d_in[8];
    const float* We = (const float*)d_in[9];
    const float* Wp = (const float*)d_in[10];
    const float* bp = (const float*)d_in[11];
    const float* g1 = (const float*)d_in[12];
    const float* b1 = (const float*)d_in[13];
    const float* g2 = (const float*)d_in[14];
    const float* b2 = (const float*)d_in[15];
    const float* W1 = (const float*)d_in[16];
    const float* b1f = (const float*)d_in[17];
    const float* W2 = (const float*)d_in[18];
    const float* b2f = (const float*)d_in[19];

    const int n = in_sizes[0] / 64;   // 50000
    const int E = in_sizes[2] / 32;   // 600000

    // Workspace carve (~90.0 MB, same total as proven layout).
    // agg (n*128 floats) ALIASES qx exactly (qx dead after k_alpha).
    char* p = (char*)d_ws;
    unsigned* qx = (unsigned*)p; p += (size_t)n * 128 * 4;   // q bf16 + wq fused
    float* aggb = (float*)qx;
    unsigned* kbf = (unsigned*)p; p += (size_t)n * 64 * 4;
    unsigned* vbf = (unsigned*)p; p += (size_t)n * 64 * 4;
    int* deg   = (int*)p;   p += (size_t)n * 4;
    p = (char*)(((uintptr_t)p + 15) & ~(uintptr_t)15);
    int* bucket = (int*)p;  p += (size_t)n * 64 * 4;
    float2* exb = (float2*)p; p += (size_t)n * 64 * 8;
    float* Wqt = (float*)p; p += 8192 * 4;
    float* Wkt = (float*)p; p += 8192 * 4;
    float* Wvt = (float*)p; p += 8192 * 4;
    float* Wet = (float*)p; p += 4096 * 4;
    float* Wpt = (float*)p; p += 8192 * 4;
    float* bqt = (float*)p; p += 128 * 4;
    float* bkt = (float*)p; p += 128 * 4;
    float* bvt = (float*)p; p += 128 * 4;

    k_pre<<<196, 256, 0, stream>>>(Wq, Wk, Wv, We, Wp, bq, bk, bv,
                                   Wqt, Wkt, Wvt, Wet, Wpt, bqt, bkt, bvt, deg, n);
    k_qkv<<<(n + 31) / 32, 256, 0, stream>>>(x, Wqt, Wkt, Wvt, bqt, bkt, bvt,
                                             g1, b1, We, qx, kbf, vbf, n);
    k_alpha<<<(E + 15) / 16, 256, 0, stream>>>(qx, kbf, ea, ei,
                                               deg, bucket, exb, E, n);
    k_agg<<<(n + 3) / 4, 256, 0, stream>>>(vbf, exb, deg, bucket, ei, ea,
                                           Wet, (float2*)aggb, n, E);
    k_post<<<(n + 255) / 256, 256, 0, stream>>>(aggb, Wpt, bp, x, g2, b2,
                                                W1, b1f, W2, b2f,
                                                (float*)d_out, n);
}

// Round 10
// 486.103 us; speedup vs baseline: 1.3299x; 1.0068x over previous
//
#include <hip/hip_runtime.h>
#include <math.h>
#include <stdint.h>

// N=50000, E=600000, IN_CH=64, HEADS=2, C=64, HC=128, EDGE_DIM=32
// Layouts:
//   qx  (uint/float mix): [node][128 dwords] = 64 uints bf16-packed q (both heads
//        per channel) followed by 64 floats wq interleaved [d*2+h]. One 512 B
//        record per node -> single contiguous tgt-side gather in k_alpha.
//   k/v (bf16 packed uint): [node][c] -> both heads at channel c in one uint
//   Wet (float2): [(d*64+c)] -> (We[d][h0*64+c], We[d][h1*64+c])
//   exb (float2): [node][slot] -> (ex_h0, ex_h1) in bucket order (unnormalized)
//   agg (float2): [node][c] -> (h0,h1); ALIASES qx exactly (dead after k_alpha).
// All data-derived indices are clamped: no input value can cause OOB.

__device__ __forceinline__ float wave_sum64(float v) {
#pragma unroll
    for (int m = 1; m < 64; m <<= 1) v += __shfl_xor(v, m);
    return v;
}

__device__ __forceinline__ unsigned pack_bf16(float2 v) {
    unsigned a = __builtin_bit_cast(unsigned, v.x);
    unsigned b = __builtin_bit_cast(unsigned, v.y);
    a = (a + 0x7FFFu + ((a >> 16) & 1u)) >> 16;   // RNE
    b = (b + 0x7FFFu + ((b >> 16) & 1u)) >> 16;
    return a | (b << 16);
}
__device__ __forceinline__ float2 unpack_bf16(unsigned p) {
    float x = __builtin_bit_cast(float, p << 16);
    float y = __builtin_bit_cast(float, p & 0xFFFF0000u);
    return make_float2(x, y);
}

// deg zero + weight re-layouts, one launch.
__global__ void k_pre(const float* __restrict__ Wq, const float* __restrict__ Wk,
                      const float* __restrict__ Wv, const float* __restrict__ We,
                      const float* __restrict__ Wp, const float* __restrict__ bq,
                      const float* __restrict__ bk, const float* __restrict__ bv,
                      float* __restrict__ Wqt, float* __restrict__ Wkt,
                      float* __restrict__ Wvt, float* __restrict__ Wet,
                      float* __restrict__ Wpt, float* __restrict__ bqt,
                      float* __restrict__ bkt, float* __restrict__ bvt,
                      int* __restrict__ deg, int n) {
    int idx = blockIdx.x * 256 + threadIdx.x;
    for (int i = idx; i < n; i += gridDim.x * 256) deg[i] = 0;
    if (idx < 8192) {
        // Wq/Wk/Wv: [cin][h*64+c] -> [cin][c*2+h]
        int cin = idx >> 7, j = idx & 127, h = j >> 6, c = j & 63;
        int dst = cin * 128 + c * 2 + h;
        Wqt[dst] = Wq[idx];
        Wkt[dst] = Wk[idx];
        Wvt[dst] = Wv[idx];
        // Wp: [h*64+c][o] -> [(c*2+h)][o]
        int jin = idx >> 6, o = idx & 63, hp = jin >> 6, cp = jin & 63;
        Wpt[(cp * 2 + hp) * 64 + o] = Wp[idx];
    }
    if (idx < 4096) {
        // We: [d][h*64+c] -> [(d*64+c)*2+h]
        int d = idx >> 7, j = idx & 127, h = j >> 6, c = j & 63;
        Wet[(d * 64 + c) * 2 + h] = We[idx];
    }
    if (idx < 128) {
        int h = idx >> 6, c = idx & 63;
        bqt[c * 2 + h] = bq[idx];
        bkt[c * 2 + h] = bk[idx];
        bvt[c * 2 + h] = bv[idx];
    }
}

// Fused LN1 + QKV + wq = We^T q. One wave per EIGHT nodes (weight reuse x8).
__global__ __launch_bounds__(256) void k_qkv(
    const float* __restrict__ x,
    const float* __restrict__ Wqt, const float* __restrict__ Wkt, const float* __restrict__ Wvt,
    const float* __restrict__ bqt, const float* __restrict__ bkt, const float* __restrict__ bvt,
    const float* __restrict__ g1, const float* __restrict__ b1,
    const float* __restrict__ We,   // original [d][h*64+c]
    unsigned* __restrict__ qx, unsigned* __restrict__ kbf,
    unsigned* __restrict__ vbf, int n) {
    __shared__ __align__(16) float hT[4][64][8];     // [wave][cin][node]  8 KB
    __shared__ __align__(16) float qs[4][2][8][64];  // [wave][h][node][c] 16 KB
    int wave = threadIdx.x >> 6, lane = threadIdx.x & 63;
    int node0 = blockIdx.x * 32 + wave * 8;
    if (node0 >= n) return;

    // ---- Phase 1: LayerNorm for 8 nodes (8 lanes per node) ----
    int b = lane >> 3, t = lane & 7;
    int nodeb = node0 + b;
    float4 xa = make_float4(0.f, 0.f, 0.f, 0.f), xb = xa;
    if (nodeb < n) {
        const float4* xp = (const float4*)(x + (size_t)nodeb * 64 + t * 8);
        xa = xp[0]; xb = xp[1];
    }
    float s1 = (xa.x + xa.y) + (xa.z + xa.w) + (xb.x + xb.y) + (xb.z + xb.w);
    float s2 = xa.x*xa.x + xa.y*xa.y + xa.z*xa.z + xa.w*xa.w
             + xb.x*xb.x + xb.y*xb.y + xb.z*xb.z + xb.w*xb.w;
#pragma unroll
    for (int m = 1; m < 8; m <<= 1) {
        s1 += __shfl_xor(s1, m);
        s2 += __shfl_xor(s2, m);
    }
    float mean = s1 * 0.015625f;
    float var  = s2 * 0.015625f - mean * mean;
    float rstd = rsqrtf(var + 1e-5f);
    float4 ga = ((const float4*)(g1 + t * 8))[0];
    float4 gb = ((const float4*)(g1 + t * 8))[1];
    float4 ba = ((const float4*)(b1 + t * 8))[0];
    float4 bb = ((const float4*)(b1 + t * 8))[1];
    float hv[8];
    hv[0] = (xa.x - mean) * rstd * ga.x + ba.x;
    hv[1] = (xa.y - mean) * rstd * ga.y + ba.y;
    hv[2] = (xa.z - mean) * rstd * ga.z + ba.z;
    hv[3] = (xa.w - mean) * rstd * ga.w + ba.w;
    hv[4] = (xb.x - mean) * rstd * gb.x + bb.x;
    hv[5] = (xb.y - mean) * rstd * gb.y + bb.y;
    hv[6] = (xb.z - mean) * rstd * gb.z + bb.z;
    hv[7] = (xb.w - mean) * rstd * gb.w + bb.w;
#pragma unroll
    for (int j = 0; j < 8; ++j) hT[wave][t * 8 + j][b] = hv[j];
    // per-wave LDS, wave-lockstep: no barrier needed

    // ---- Phase 2: QKV projection, 8 nodes per weight load ----
    const float2* Wq2 = (const float2*)Wqt;
    const float2* Wk2 = (const float2*)Wkt;
    const float2* Wv2 = (const float2*)Wvt;
    float2 bqv = ((const float2*)bqt)[lane];
    float2 bkv = ((const float2*)bkt)[lane];
    float2 bvv = ((const float2*)bvt)[lane];
    float2 qa[8], ka[8], va[8];
#pragma unroll
    for (int nb = 0; nb < 8; ++nb) { qa[nb] = bqv; ka[nb] = bkv; va[nb] = bvv; }

#pragma unroll 4
    for (int cin = 0; cin < 64; ++cin) {
        float2 w_q = Wq2[cin * 64 + lane];
        float2 w_k = Wk2[cin * 64 + lane];
        float2 w_v = Wv2[cin * 64 + lane];
        const float4* hp = (const float4*)&hT[wave][cin][0];
        float4 h0 = hp[0], h1 = hp[1];   // b128 broadcast
        float hs[8] = {h0.x, h0.y, h0.z, h0.w, h1.x, h1.y, h1.z, h1.w};
#pragma unroll
        for (int nb = 0; nb < 8; ++nb) {
            qa[nb].x += hs[nb] * w_q.x; qa[nb].y += hs[nb] * w_q.y;
            ka[nb].x += hs[nb] * w_k.x; ka[nb].y += hs[nb] * w_k.y;
            va[nb].x += hs[nb] * w_v.x; va[nb].y += hs[nb] * w_v.y;
        }
    }

    // ---- Phase 3: stores + stage q in LDS for phase 4 ----
#pragma unroll
    for (int nb = 0; nb < 8; ++nb) {
        int nd = node0 + nb;
        if (nd < n) {
            qx[(size_t)nd * 128 + lane] = pack_bf16(qa[nb]);
            kbf[(size_t)nd * 64 + lane] = pack_bf16(ka[nb]);
            vbf[(size_t)nd * 64 + lane] = pack_bf16(va[nb]);
        }
        qs[wave][0][nb][lane] = qa[nb].x;
        qs[wave][1][nb][lane] = qa[nb].y;
    }

    // ---- Phase 4: wq = We^T q -> qx[node][64 + d*2 + h], 8 nodes per We load ----
    int hh = lane >> 5, d = lane & 31;
    const float4* Wr = (const float4*)(We + d * 128 + hh * 64);
    float wqa[8] = {0.f, 0.f, 0.f, 0.f, 0.f, 0.f, 0.f, 0.f};
#pragma unroll 4
    for (int c4 = 0; c4 < 16; ++c4) {
        float4 w = Wr[c4];
#pragma unroll
        for (int nb = 0; nb < 8; ++nb) {
            float4 qv = *(const float4*)&qs[wave][hh][nb][c4 * 4];  // broadcast
            wqa[nb] += w.x * qv.x + w.y * qv.y + w.z * qv.z + w.w * qv.w;
        }
    }
#pragma unroll
    for (int nb = 0; nb < 8; ++nb)
        if (node0 + nb < n)
            ((float*)qx)[(size_t)(node0 + nb) * 128 + 64 + d * 2 + hh] = wqa[nb];
}

// Edge-parallel alpha + bucket build. FOUR edges per wave (16 lanes each).
__global__ __launch_bounds__(256) void k_alpha(
    const unsigned* __restrict__ qx, const unsigned* __restrict__ kbf,
    const float* __restrict__ edge_attr,
    const int* __restrict__ ei, int* __restrict__ deg,
    int* __restrict__ bucket, float2* __restrict__ exb, int E, int n) {
    int wave = threadIdx.x >> 6, lane = threadIdx.x & 63;
    int sub = lane >> 4, l = lane & 15;
    int e = blockIdx.x * 16 + wave * 4 + sub;
    bool evalid = e < E;
    int ec = min(e, E - 1);

    int src = ei[ec];          // 16 lanes same addr -> broadcast transaction
    int tgt = ei[E + ec];
    src = min(max(src, 0), n - 1);
    tgt = min(max(tgt, 0), n - 1);

    const uint4* qx4 = (const uint4*)qx;
    uint4 qq = qx4[(size_t)tgt * 32 + l];              // q channels 4l..4l+3
    float4 w = ((const float4*)qx)[(size_t)tgt * 32 + 16 + l];  // wq dims 2l,2l+1
    uint4 kk = ((const uint4*)kbf)[(size_t)src * 16 + l];
    float2 a = ((const float2*)edge_attr)[(size_t)ec * 16 + l];

    float2 q0 = unpack_bf16(qq.x), q1 = unpack_bf16(qq.y),
           q2 = unpack_bf16(qq.z), q3 = unpack_bf16(qq.w);
    float2 k0 = unpack_bf16(kk.x), k1 = unpack_bf16(kk.y),
           k2 = unpack_bf16(kk.z), k3 = unpack_bf16(kk.w);

    float r0 = q0.x * k0.x + q1.x * k1.x + q2.x * k2.x + q3.x * k3.x
             + w.x * a.x + w.z * a.y;
    float r1 = q0.y * k0.y + q1.y * k1.y + q2.y * k2.y + q3.y * k3.y
             + w.y * a.x + w.w * a.y;
#pragma unroll
    for (int m = 1; m < 16; m <<= 1) {   // masks 1..8 stay within the 16-lane group
        r0 += __shfl_xor(r0, m);
        r1 += __shfl_xor(r1, m);
    }
    if (l == 0 && evalid) {
        int slot = atomicAdd(&deg[tgt], 1);
        if (slot < 64) {
            bucket[(size_t)tgt * 64 + slot] = ec;
            exb[(size_t)tgt * 64 + slot] =
                make_float2(__expf(r0 * 0.125f), __expf(r1 * 0.125f));
        }
    }
}

// Attention aggregation only (epilogue in k_post). One wave per node.
__global__ __launch_bounds__(256) void k_agg(
    const unsigned* __restrict__ vbf, const float2* __restrict__ exb,
    const int* __restrict__ deg, const int* __restrict__ bucket,
    const int* __restrict__ ei, const float* __restrict__ edge_attr,
    const float* __restrict__ Wet,   // float2 per (d*64+c)
    float2* __restrict__ agg, int n, int E) {
    __shared__ __align__(16) float sbuf[4][64];
    int wave = threadIdx.x >> 6, lane = threadIdx.x & 63;
    int node = blockIdx.x * 4 + wave;
    if (node >= n) return;

    int dl = lane & 31, hh = lane >> 5;

    // Coalesced preamble: lane i holds edge i's id, src, and ex pair.
    int dcount = min(deg[node], 64);
    int eid_l = 0, src_l = 0;
    float2 exl = make_float2(0.f, 0.f);
    if (lane < dcount) {
        eid_l = bucket[(size_t)node * 64 + lane];
        eid_l = min(max(eid_l, 0), E - 1);
        src_l = ei[eid_l];
        src_l = min(max(src_l, 0), n - 1);
        exl = exb[(size_t)node * 64 + lane];
    }
    float den0 = wave_sum64(exl.x);
    float den1 = wave_sum64(exl.y);

    // Padded 4-wide loop: lanes >= dcount contribute ex=0 -> zero contribution.
    float acc0 = 0.f, acc1 = 0.f, S = 0.f;
    int rounds = (dcount + 3) >> 2;
    for (int r = 0; r < rounds; ++r) {
        int i = r * 4;
        int e0 = __shfl(eid_l, i),     e1 = __shfl(eid_l, i + 1),
            e2 = __shfl(eid_l, i + 2), e3 = __shfl(eid_l, i + 3);
        int s0 = __shfl(src_l, i),     s1 = __shfl(src_l, i + 1),
            s2 = __shfl(src_l, i + 2), s3 = __shfl(src_l, i + 3);
        float x0 = __shfl(exl.x, i),     y0 = __shfl(exl.y, i);
        float x1 = __shfl(exl.x, i + 1), y1 = __shfl(exl.y, i + 1);
        float x2 = __shfl(exl.x, i + 2), y2 = __shfl(exl.y, i + 2);
        float x3 = __shfl(exl.x, i + 3), y3 = __shfl(exl.y, i + 3);
        float2 u0 = unpack_bf16(vbf[(size_t)s0 * 64 + lane]);
        float2 u1 = unpack_bf16(vbf[(size_t)s1 * 64 + lane]);
        float2 u2 = unpack_bf16(vbf[(size_t)s2 * 64 + lane]);
        float2 u3 = unpack_bf16(vbf[(size_t)s3 * 64 + lane]);
        float a0 = edge_attr[(size_t)e0 * 32 + dl];
        float a1 = edge_attr[(size_t)e1 * 32 + dl];
        float a2 = edge_attr[(size_t)e2 * 32 + dl];
        float a3 = edge_attr[(size_t)e3 * 32 + dl];
        acc0 += x0 * u0.x; acc1 += y0 * u0.y;
        acc0 += x1 * u1.x; acc1 += y1 * u1.y;
        acc0 += x2 * u2.x; acc1 += y2 * u2.y;
        acc0 += x3 * u3.x; acc1 += y3 * u3.y;
        S += (hh ? y0 : x0) * a0;
        S += (hh ? y1 : x1) * a1;
        S += (hh ? y2 : x2) * a2;
        S += (hh ? y3 : x3) * a3;
    }

    // B = We^T S : S to LDS interleaved [d*2+h], then per-lane 64 FMA.
    float* row = sbuf[wave];
    row[dl * 2 + hh] = S;
    float B0 = 0.f, B1 = 0.f;
    const float2* We2 = (const float2*)Wet;
    const float2* S2 = (const float2*)row;
#pragma unroll
    for (int d = 0; d < 32; ++d) {
        float2 w = We2[d * 64 + lane];
        float2 s = S2[d];   // LDS b64 broadcast
        B0 += w.x * s.x;
        B1 += w.y * s.y;
    }
    float r0 = 1.0f / (den0 + 1e-8f);
    float r1 = 1.0f / (den1 + 1e-8f);
    agg[(size_t)node * 64 + lane] = make_float2((acc0 + B0) * r0, (acc1 + B1) * r1);
}

// Epilogue v2: EIGHT threads per node (8 output channels each) for occupancy.
// Lane layout: nl=lane>>3 (node in wave), g=lane&7 (channel octet). Weight
// addresses are uniform within each 8-lane group -> broadcast VMEM segments,
// each weight row fetched once per 8 nodes. Node rows staged in wave-local LDS
// ([8][132] stride -> bank (4*nl+c)%32: conflict-free b128, group broadcast).
// LN2 via 3-step shfl_xor (masks 1,2,4 stay inside the 8-lane group).
__global__ __launch_bounds__(256) void k_post(
    const float* __restrict__ agg,   // [node][128], cin = c*2+h
    const float* __restrict__ Wpt,   // [cin][64]
    const float* __restrict__ bp, const float* __restrict__ x,
    const float* __restrict__ g2, const float* __restrict__ b2,
    const float* __restrict__ W1, const float* __restrict__ b1f,
    const float* __restrict__ W2, const float* __restrict__ b2f,
    float* __restrict__ out, int n) {
    __shared__ __align__(16) float rows[4][8][132];   // 16.9 KB
    int wave = threadIdx.x >> 6, lane = threadIdx.x & 63;
    int nl = lane >> 3, g = lane & 7;
    int node = blockIdx.x * 32 + wave * 8 + nl;
    bool valid = node < n;
    int nd = min(node, n - 1);
    float* row = rows[wave][nl];

    // Stage agg row: 16 floats per thread, coalesced global -> LDS.
    {
        const float4* ap = (const float4*)(agg + (size_t)nd * 128 + g * 16);
        float4 a0 = ap[0], a1 = ap[1], a2 = ap[2], a3 = ap[3];
        float4* rp = (float4*)(row + g * 16);
        rp[0] = a0; rp[1] = a1; rp[2] = a2; rp[3] = a3;
    }

    // acc = bp + x (residual 1)
    float acc[8];
    {
        const float4* xp = (const float4*)(x + (size_t)nd * 64 + g * 8);
        float4 x0 = xp[0], x1 = xp[1];
        const float4* bpp = (const float4*)(bp + g * 8);
        float4 b0 = bpp[0], b1v = bpp[1];
        acc[0] = b0.x + x0.x;  acc[1] = b0.y + x0.y;
        acc[2] = b0.z + x0.z;  acc[3] = b0.w + x0.w;
        acc[4] = b1v.x + x1.x; acc[5] = b1v.y + x1.y;
        acc[6] = b1v.z + x1.z; acc[7] = b1v.w + x1.w;
    }

    // acc += agg @ Wp   (128 cins; agg via LDS b128 broadcast, Wp group-uniform)
#pragma unroll 4
    for (int c4 = 0; c4 < 32; ++c4) {
        float4 a = *(const float4*)(row + c4 * 4);
        float as[4] = {a.x, a.y, a.z, a.w};
#pragma unroll
        for (int j = 0; j < 4; ++j) {
            const float4* wp = (const float4*)(Wpt + (c4 * 4 + j) * 64 + g * 8);
            float4 w0 = wp[0], w1 = wp[1];
            acc[0] += as[j] * w0.x; acc[1] += as[j] * w0.y;
            acc[2] += as[j] * w0.z; acc[3] += as[j] * w0.w;
            acc[4] += as[j] * w1.x; acc[5] += as[j] * w1.y;
            acc[6] += as[j] * w1.z; acc[7] += as[j] * w1.w;
        }
    }

    // LN2: 8 local + 3-step group reduction
    float s1 = 0.f, s2 = 0.f;
#pragma unroll
    for (int c = 0; c < 8; ++c) { s1 += acc[c]; s2 += acc[c] * acc[c]; }
#pragma unroll
    for (int m = 1; m < 8; m <<= 1) {
        s1 += __shfl_xor(s1, m);
        s2 += __shfl_xor(s2, m);
    }
    float mean = s1 * 0.015625f;
    float var  = s2 * 0.015625f - mean * mean;
    float rstd = rsqrtf(var + 1e-5f);
    {
        const float4* gp = (const float4*)(g2 + g * 8);
        const float4* bpp = (const float4*)(b2 + g * 8);
        float4 ga = gp[0], gb = gp[1], ba = bpp[0], bb = bpp[1];
        float h2[8];
        h2[0] = (acc[0] - mean) * rstd * ga.x + ba.x;
        h2[1] = (acc[1] - mean) * rstd * ga.y + ba.y;
        h2[2] = (acc[2] - mean) * rstd * ga.z + ba.z;
        h2[3] = (acc[3] - mean) * rstd * ga.w + ba.w;
        h2[4] = (acc[4] - mean) * rstd * gb.x + bb.x;
        h2[5] = (acc[5] - mean) * rstd * gb.y + bb.y;
        h2[6] = (acc[6] - mean) * rstd * gb.z + bb.z;
        h2[7] = (acc[7] - mean) * rstd * gb.w + bb.w;
        float4* rp = (float4*)(row + g * 8);    // h2 at row[0..63]
        rp[0] = make_float4(h2[0], h2[1], h2[2], h2[3]);
        rp[1] = make_float4(h2[4], h2[5], h2[6], h2[7]);
    }

    // f = h2 @ W1 + b1; gelu -> row[64..127]
    float f[8];
    {
        const float4* bpp = (const float4*)(b1f + g * 8);
        float4 b0 = bpp[0], b1v = bpp[1];
        f[0] = b0.x;  f[1] = b0.y;  f[2] = b0.z;  f[3] = b0.w;
        f[4] = b1v.x; f[5] = b1v.y; f[6] = b1v.z; f[7] = b1v.w;
    }
#pragma unroll 4
    for (int c4 = 0; c4 < 16; ++c4) {
        float4 a = *(const float4*)(row + c4 * 4);
        float as[4] = {a.x, a.y, a.z, a.w};
#pragma unroll
        for (int j = 0; j < 4; ++j) {
            const float4* wp = (const float4*)(W1 + (c4 * 4 + j) * 64 + g * 8);
            float4 w0 = wp[0], w1 = wp[1];
            f[0] += as[j] * w0.x; f[1] += as[j] * w0.y;
            f[2] += as[j] * w0.z; f[3] += as[j] * w0.w;
            f[4] += as[j] * w1.x; f[5] += as[j] * w1.y;
            f[6] += as[j] * w1.z; f[7] += as[j] * w1.w;
        }
    }
#pragma unroll
    for (int c = 0; c < 8; ++c)
        f[c] = 0.5f * f[c] * (1.0f + erff(f[c] * 0.70710678118654752f));
    {
        float4* rp = (float4*)(row + 64 + g * 8);
        rp[0] = make_float4(f[0], f[1], f[2], f[3]);
        rp[1] = make_float4(f[4], f[5], f[6], f[7]);
    }

    // y = gelu @ W2 + b2f + acc (residual 2)
    float y[8];
    {
        const float4* bpp = (const float4*)(b2f + g * 8);
        float4 b0 = bpp[0], b1v = bpp[1];
        y[0] = b0.x + acc[0];  y[1] = b0.y + acc[1];
        y[2] = b0.z + acc[2];  y[3] = b0.w + acc[3];
        y[4] = b1v.x + acc[4]; y[5] = b1v.y + acc[5];
        y[6] = b1v.z + acc[6]; y[7] = b1v.w + acc[7];
    }
#pragma unroll 4
    for (int c4 = 0; c4 < 16; ++c4) {
        float4 a = *(const float4*)(row + 64 + c4 * 4);
        float as[4] = {a.x, a.y, a.z, a.w};
#pragma unroll
        for (int j = 0; j < 4; ++j) {
            const float4* wp = (const float4*)(W2 + (c4 * 4 + j) * 64 + g * 8);
            float4 w0 = wp[0], w1 = wp[1];
            y[0] += as[j] * w0.x; y[1] += as[j] * w0.y;
            y[2] += as[j] * w0.z; y[3] += as[j] * w0.w;
            y[4] += as[j] * w1.x; y[5] += as[j] * w1.y;
            y[6] += as[j] * w1.z; y[7] += as[j] * w1.w;
        }
    }

    if (valid) {
        float4* op = (float4*)(out + (size_t)node * 64 + g * 8);
        op[0] = make_float4(y[0], y[1], y[2], y[3]);
        op[1] = make_float4(y[4], y[5], y[6], y[7]);
    }
}

extern "C" void kernel_launch(void* const* d_in, const int* in_sizes, int n_in,
                              void* d_out, int out_size, void* d_ws, size_t ws_size,
                              hipStream_t stream) {
    const float* x  = (const float*)d_in[0];
    const int*   ei = (const int*)d_in[1];
    const float* ea = (const float*)d_in[2];
    const float* Wq = (const float*)d_in[3];
    const float* bq = (const float*)d_in[4];
    const float* Wk = (const float*)d_in[5];
    const float* bk = (const float*)d_in[6];
    const float* Wv = (const float*)d_in[7];
    const float* bv = (const float*)d_in[8];
    const float* We = (const float*)d_in[9];
    const float* Wp = (const float*)d_in[10];
    const float* bp = (const float*)d_in[11];
    const float* g1 = (const float*)d_in[12];
    const float* b1 = (const float*)d_in[13];
    const float* g2 = (const float*)d_in[14];
    const float* b2 = (const float*)d_in[15];
    const float* W1 = (const float*)d_in[16];
    const float* b1f = (const float*)d_in[17];
    const float* W2 = (const float*)d_in[18];
    const float* b2f = (const float*)d_in[19];

    const int n = in_sizes[0] / 64;   // 50000
    const int E = in_sizes[2] / 32;   // 600000

    // Workspace carve (~90.0 MB, proven layout).
    // agg (n*128 floats) ALIASES qx exactly (qx dead after k_alpha).
    char* p = (char*)d_ws;
    unsigned* qx = (unsigned*)p; p += (size_t)n * 128 * 4;   // q bf16 + wq fused
    float* aggb = (float*)qx;
    unsigned* kbf = (unsigned*)p; p += (size_t)n * 64 * 4;
    unsigned* vbf = (unsigned*)p; p += (size_t)n * 64 * 4;
    int* deg   = (int*)p;   p += (size_t)n * 4;
    p = (char*)(((uintptr_t)p + 15) & ~(uintptr_t)15);
    int* bucket = (int*)p;  p += (size_t)n * 64 * 4;
    float2* exb = (float2*)p; p += (size_t)n * 64 * 8;
    float* Wqt = (float*)p; p += 8192 * 4;
    float* Wkt = (float*)p; p += 8192 * 4;
    float* Wvt = (float*)p; p += 8192 * 4;
    float* Wet = (float*)p; p += 4096 * 4;
    float* Wpt = (float*)p; p += 8192 * 4;
    float* bqt = (float*)p; p += 128 * 4;
    float* bkt = (float*)p; p += 128 * 4;
    float* bvt = (float*)p; p += 128 * 4;

    k_pre<<<196, 256, 0, stream>>>(Wq, Wk, Wv, We, Wp, bq, bk, bv,
                                   Wqt, Wkt, Wvt, Wet, Wpt, bqt, bkt, bvt, deg, n);
    k_qkv<<<(n + 31) / 32, 256, 0, stream>>>(x, Wqt, Wkt, Wvt, bqt, bkt, bvt,
                                             g1, b1, We, qx, kbf, vbf, n);
    k_alpha<<<(E + 15) / 16, 256, 0, stream>>>(qx, kbf, ea, ei,
                                               deg, bucket, exb, E, n);
    k_agg<<<(n + 3) / 4, 256, 0, stream>>>(vbf, exb, deg, bucket, ei, ea,
                                           Wet, (float2*)aggb, n, E);
    k_post<<<(n + 31) / 32, 256, 0, stream>>>(aggb, Wpt, bp, x, g2, b2,
                                              W1, b1f, W2, b2f,
                                              (float*)d_out, n);
}